// Round 1
// baseline (1863.472 us; speedup 1.0000x reference)
//
#include <hip/hip_runtime.h>

#define N_CLASS 10
#define HIDDEN 128
#define BN_EPS 1e-5f

// ---------------------------------------------------------------------------
// out[dst] += X[src] over E edges, D features each. One thread per (edge,feat).
// Consecutive threads -> consecutive features of same edge -> coalesced atomics.
// ---------------------------------------------------------------------------
template<int D>
__global__ void scatter_add_k(const float* __restrict__ X, const int* __restrict__ ei,
                              float* __restrict__ out, int E) {
    int t = blockIdx.x * blockDim.x + threadIdx.x;
    if (t >= E * D) return;                 // E*D <= 204.8M, fits in int
    int e = t / D;
    int f = t - e * D;
    int s = ei[e];
    int d = ei[E + e];
    atomicAdd(out + (size_t)d * D + f, X[(size_t)s * D + f]);
}

// ---------------------------------------------------------------------------
// C[N,128] = A[N,K] @ W[K,128] + bias.  W cached in LDS, ROWS rows per iter.
// block = 128 threads, thread t owns output column t.
// ---------------------------------------------------------------------------
template<int K, int ROWS>
__global__ __launch_bounds__(128) void gemm_bias_k(
    const float* __restrict__ A, const float* __restrict__ W,
    const float* __restrict__ bias, float* __restrict__ C, int N) {
    __shared__ float Wl[K * HIDDEN];
    __shared__ float bl[HIDDEN];
    __shared__ float rb[ROWS * K];
    const int tid = threadIdx.x;
    for (int i = tid; i < K * HIDDEN; i += 128) Wl[i] = W[i];
    bl[tid] = bias[tid];
    __syncthreads();

    for (int r0 = blockIdx.x * ROWS; r0 < N; r0 += gridDim.x * ROWS) {
        int nr = min(ROWS, N - r0);
        for (int i = tid; i < nr * K; i += 128)
            rb[i] = A[(size_t)r0 * K + i];      // rows are contiguous
        __syncthreads();
        float acc[ROWS];
#pragma unroll
        for (int r = 0; r < ROWS; ++r) acc[r] = bl[tid];
        for (int k = 0; k < K; ++k) {
            float w = Wl[k * HIDDEN + tid];     // consecutive lanes, 2-way free
#pragma unroll
            for (int r = 0; r < ROWS; ++r)
                acc[r] = fmaf(rb[r * K + k], w, acc[r]);  // broadcast read
        }
#pragma unroll
        for (int r = 0; r < ROWS; ++r)
            if (r < nr) C[(size_t)(r0 + r) * HIDDEN + tid] = acc[r];
        __syncthreads();
    }
}

// ---------------------------------------------------------------------------
// Per-column sum and sum-of-squares over N rows -> st[0:128], st[128:256]
// ---------------------------------------------------------------------------
__global__ void colstats_k(const float* __restrict__ Z, float* __restrict__ st, int N) {
    const int col = threadIdx.x;           // 128 threads
    float s = 0.f, s2 = 0.f;
    for (int r = blockIdx.x; r < N; r += gridDim.x) {
        float v = Z[(size_t)r * HIDDEN + col];
        s += v;
        s2 += v * v;
    }
    atomicAdd(st + col, s);
    atomicAdd(st + HIDDEN + col, s2);
}

// ---------------------------------------------------------------------------
// In-place BatchNorm(train, biased var) + ReLU
// ---------------------------------------------------------------------------
__global__ void bnrelu_k(float* __restrict__ Z, const float* __restrict__ st,
                         const float* __restrict__ g, const float* __restrict__ b,
                         int N) {
    int i = blockIdx.x * blockDim.x + threadIdx.x;
    if (i >= N * HIDDEN) return;
    int col = i & (HIDDEN - 1);
    float inv_n = 1.0f / (float)N;
    float m   = st[col] * inv_n;
    float var = fmaxf(st[HIDDEN + col] * inv_n - m * m, 0.f);
    float y   = g[col] * (Z[i] - m) * rsqrtf(var + BN_EPS) + b[col];
    Z[i] = fmaxf(y, 0.f);
}

// ---------------------------------------------------------------------------
// out = log_softmax(H @ wf + bf).  One 64-lane wave per node; shuffle-reduce.
// ---------------------------------------------------------------------------
__global__ void final_lsm_k(const float* __restrict__ H, const float* __restrict__ wf,
                            const float* __restrict__ bf, float* __restrict__ out, int N) {
    int gid  = blockIdx.x * blockDim.x + threadIdx.x;
    int node = gid >> 6;
    int lane = gid & 63;
    if (node >= N) return;
    const float* h = H + (size_t)node * HIDDEN;
    float a0 = h[lane];
    float a1 = h[lane + 64];
    float logit[N_CLASS];
#pragma unroll
    for (int c = 0; c < N_CLASS; ++c) {
        float p = fmaf(a0, wf[lane * N_CLASS + c], a1 * wf[(lane + 64) * N_CLASS + c]);
#pragma unroll
        for (int off = 32; off; off >>= 1) p += __shfl_down(p, off);
        logit[c] = p + bf[c];
    }
    if (lane == 0) {
        float m = logit[0];
#pragma unroll
        for (int c = 1; c < N_CLASS; ++c) m = fmaxf(m, logit[c]);
        float s = 0.f;
#pragma unroll
        for (int c = 0; c < N_CLASS; ++c) s += expf(logit[c] - m);
        float lse = logf(s);
#pragma unroll
        for (int c = 0; c < N_CLASS; ++c)
            out[(size_t)node * N_CLASS + c] = logit[c] - m - lse;
    }
}

// ---------------------------------------------------------------------------

extern "C" void kernel_launch(void* const* d_in, const int* in_sizes, int n_in,
                              void* d_out, int out_size, void* d_ws, size_t ws_size,
                              hipStream_t stream) {
    const float* x   = (const float*)d_in[0];
    // d_in[1] edge_weight: unused by the reference
    const float* w11 = (const float*)d_in[2];
    const float* b11 = (const float*)d_in[3];
    const float* g11 = (const float*)d_in[4];
    const float* t11 = (const float*)d_in[5];
    const float* w12 = (const float*)d_in[6];
    const float* b12 = (const float*)d_in[7];
    const float* g12 = (const float*)d_in[8];
    const float* t12 = (const float*)d_in[9];
    const float* w21 = (const float*)d_in[10];
    const float* b21 = (const float*)d_in[11];
    const float* g21 = (const float*)d_in[12];
    const float* t21 = (const float*)d_in[13];
    const float* w22 = (const float*)d_in[14];
    const float* b22 = (const float*)d_in[15];
    const float* g22 = (const float*)d_in[16];
    const float* t22 = (const float*)d_in[17];
    const float* wf  = (const float*)d_in[18];
    const float* bf  = (const float*)d_in[19];
    const int*   ei  = (const int*)d_in[20];

    const int N = in_sizes[0] / N_CLASS;     // 100000
    const int E = in_sizes[1];               // 1600000

    // workspace layout (floats)
    float* ws    = (float*)d_ws;
    float* stats = ws;                                   // 4 sets x 256 floats
    float* h0    = ws + 1024;                            // N*10
    size_t off   = 1024 + (((size_t)N * N_CLASS + 255) / 256) * 256;
    float* P     = ws + off;                             // N*128
    float* Q     = P + (size_t)N * HIDDEN;               // N*128

    const int elem128 = N * HIDDEN;

    hipMemsetAsync(stats, 0, 1024 * sizeof(float), stream);

    // ---- layer 1 aggregation: h0 = x + scatter(x) ----
    hipMemcpyAsync(h0, x, (size_t)N * N_CLASS * sizeof(float),
                   hipMemcpyDeviceToDevice, stream);
    scatter_add_k<N_CLASS><<<(E * N_CLASS + 255) / 256, 256, 0, stream>>>(x, ei, h0, E);

    // ---- layer 1 MLP ----
    gemm_bias_k<N_CLASS, 4><<<2048, 128, 0, stream>>>(h0, w11, b11, P, N);
    colstats_k<<<1024, 128, 0, stream>>>(P, stats, N);
    bnrelu_k<<<(elem128 + 255) / 256, 256, 0, stream>>>(P, stats, g11, t11, N);

    gemm_bias_k<HIDDEN, 4><<<512, 128, 0, stream>>>(P, w12, b12, Q, N);
    colstats_k<<<1024, 128, 0, stream>>>(Q, stats + 256, N);
    bnrelu_k<<<(elem128 + 255) / 256, 256, 0, stream>>>(Q, stats + 256, g12, t12, N);

    // ---- layer 2 aggregation: P = Q + scatter(Q) ----
    hipMemcpyAsync(P, Q, (size_t)elem128 * sizeof(float),
                   hipMemcpyDeviceToDevice, stream);
    {
        int total = E * HIDDEN;                          // 204.8M
        scatter_add_k<HIDDEN><<<(total + 255) / 256, 256, 0, stream>>>(Q, ei, P, E);
    }

    // ---- layer 2 MLP ----
    gemm_bias_k<HIDDEN, 4><<<512, 128, 0, stream>>>(P, w21, b21, Q, N);
    colstats_k<<<1024, 128, 0, stream>>>(Q, stats + 512, N);
    bnrelu_k<<<(elem128 + 255) / 256, 256, 0, stream>>>(Q, stats + 512, g21, t21, N);

    gemm_bias_k<HIDDEN, 4><<<512, 128, 0, stream>>>(Q, w22, b22, P, N);
    colstats_k<<<1024, 128, 0, stream>>>(P, stats + 768, N);
    bnrelu_k<<<(elem128 + 255) / 256, 256, 0, stream>>>(P, stats + 768, g22, t22, N);

    // ---- final linear + log_softmax ----
    final_lsm_k<<<(N * 64 + 255) / 256, 256, 0, stream>>>(P, wf, bf, (float*)d_out, N);
}

// Round 3
// 988.651 us; speedup vs baseline: 1.8849x; 1.8849x over previous
//
#include <hip/hip_runtime.h>

#define N_CLASS 10
#define HIDDEN 128
#define BN_EPS 1e-5f

// ============================ CSR build =====================================
__global__ void hist_k(const int* __restrict__ ei, int* __restrict__ cnt, int E) {
    int e = blockIdx.x * 256 + threadIdx.x;
    if (e < E) atomicAdd(cnt + ei[E + e], 1);
}

__global__ void scanA_k(const int* __restrict__ cnt, int* __restrict__ bsum, int N) {
    __shared__ int sm[256];
    int i = blockIdx.x * 256 + threadIdx.x;
    sm[threadIdx.x] = (i < N) ? cnt[i] : 0;
    __syncthreads();
    for (int s = 128; s > 0; s >>= 1) {
        if (threadIdx.x < s) sm[threadIdx.x] += sm[threadIdx.x + s];
        __syncthreads();
    }
    if (threadIdx.x == 0) bsum[blockIdx.x] = sm[0];
}

// exclusive scan of bsum[0..B-1], B <= 512, one block of 512 threads
__global__ void scanB_k(int* __restrict__ bsum, int B) {
    __shared__ int sm[512];
    int t = threadIdx.x;
    sm[t] = (t < B) ? bsum[t] : 0;
    __syncthreads();
    for (int off = 1; off < 512; off <<= 1) {
        int u = (t >= off) ? sm[t - off] : 0;
        __syncthreads();
        sm[t] += u;
        __syncthreads();
    }
    if (t < B) bsum[t] = (t == 0) ? 0 : sm[t - 1];
}

__global__ void scanC_k(const int* __restrict__ cnt, const int* __restrict__ boff,
                        int* __restrict__ row_ptr, int N) {
    __shared__ int sm[256];
    int i = blockIdx.x * 256 + threadIdx.x;
    int t = threadIdx.x;
    int v = (i < N) ? cnt[i] : 0;
    sm[t] = v;
    __syncthreads();
    for (int off = 1; off < 256; off <<= 1) {
        int u = (t >= off) ? sm[t - off] : 0;
        __syncthreads();
        sm[t] += u;
        __syncthreads();
    }
    if (i < N) row_ptr[i] = boff[blockIdx.x] + sm[t] - v;   // exclusive
}

__global__ void fill_k(const int* __restrict__ ei, int* __restrict__ cursor,
                       int* __restrict__ col, int E) {
    int e = blockIdx.x * 256 + threadIdx.x;
    if (e < E) {
        int p = atomicAdd(cursor + ei[E + e], 1);
        col[p] = ei[e];
    }
}

// ===================== layer-1 gather: h0 = x + sum x[src] ==================
__global__ void gather10_k(const float* __restrict__ X, const int* __restrict__ col,
                           const int* __restrict__ rp, const int* __restrict__ cnt,
                           float* __restrict__ out, int N) {
    int t = blockIdx.x * 256 + threadIdx.x;
    int node = t / N_CLASS, f = t - node * N_CLASS;
    if (node >= N) return;
    int start = rp[node], deg = cnt[node];
    float acc = X[(size_t)node * N_CLASS + f];
    for (int j = 0; j < deg; ++j)
        acc += X[(size_t)col[start + j] * N_CLASS + f];
    out[(size_t)node * N_CLASS + f] = acc;
}

// ========== layer-2 gather with fused BN+ReLU on every element read =========
// out[n] = bnrelu(X[n]) + sum_j bnrelu(X[col[j]]);  one wave per node, float2/lane
__global__ __launch_bounds__(256) void gather_bn_k(
    const float* __restrict__ X, const int* __restrict__ col,
    const int* __restrict__ rp, const int* __restrict__ cnt,
    const float* __restrict__ st, const float* __restrict__ g,
    const float* __restrict__ b, float* __restrict__ out, int N, float inv_n) {
    int wave = (blockIdx.x * 256 + threadIdx.x) >> 6;
    int lane = threadIdx.x & 63;
    if (wave >= N) return;
    int c0 = lane * 2;
    float m0 = st[c0] * inv_n,      m1 = st[c0 + 1] * inv_n;
    float v0 = fmaxf(st[128 + c0] * inv_n - m0 * m0, 0.f);
    float v1 = fmaxf(st[128 + c0 + 1] * inv_n - m1 * m1, 0.f);
    float s0 = g[c0] * rsqrtf(v0 + BN_EPS), s1 = g[c0 + 1] * rsqrtf(v1 + BN_EPS);
    float h0 = b[c0] - m0 * s0,            h1 = b[c0 + 1] - m1 * s1;
    int start = rp[wave], deg = cnt[wave];
    const float2* Xv = (const float2*)X;
    float2 self = Xv[(size_t)wave * 64 + lane];
    float a0 = fmaxf(fmaf(self.x, s0, h0), 0.f);
    float a1 = fmaxf(fmaf(self.y, s1, h1), 0.f);
    for (int j = 0; j < deg; ++j) {
        int s = col[start + j];
        float2 v = Xv[(size_t)s * 64 + lane];
        a0 += fmaxf(fmaf(v.x, s0, h0), 0.f);
        a1 += fmaxf(fmaf(v.y, s1, h1), 0.f);
    }
    float2 o; o.x = a0; o.y = a1;
    ((float2*)out)[(size_t)wave * 64 + lane] = o;
}

// ================= K=10 GEMM + bias + column-stats epilogue =================
__global__ __launch_bounds__(128) void gemm10_k(
    const float* __restrict__ A, const float* __restrict__ W,
    const float* __restrict__ bias, float* __restrict__ C,
    float* __restrict__ stOut, int N) {
    __shared__ float rb[16 * N_CLASS];
    const int tid = threadIdx.x;
    float wreg[N_CLASS];
#pragma unroll
    for (int k = 0; k < N_CLASS; ++k) wreg[k] = W[k * HIDDEN + tid];
    float bb = bias[tid];
    float s = 0.f, s2 = 0.f;
    for (int r0 = blockIdx.x * 16; r0 < N; r0 += gridDim.x * 16) {
        int nr = min(16, N - r0);
        for (int i = tid; i < nr * N_CLASS; i += 128) rb[i] = A[r0 * N_CLASS + i];
        __syncthreads();
        for (int r = 0; r < nr; ++r) {
            float acc = bb;
#pragma unroll
            for (int k = 0; k < N_CLASS; ++k) acc = fmaf(rb[r * N_CLASS + k], wreg[k], acc);
            C[(size_t)(r0 + r) * HIDDEN + tid] = acc;
            s += acc; s2 += acc * acc;
        }
        __syncthreads();
    }
    atomicAdd(stOut + tid, s);
    atomicAdd(stOut + HIDDEN + tid, s2);
}

// ====== K=128 register-tiled GEMM, optional fused input-BN+ReLU, stats ======
// 256 threads: cg = tid>>3 (col group, 4 cols), rg = tid&7 (row group, 4 rows)
// tile = 32 rows x 128 cols, K in 2 chunks of 64.
// A chunk stored transposed+XOR-swizzled: At[k][ r ^ (k&31) ] -> both the
// staging writes and the b128 reads are bank-conflict-free; the XOR of the low
// 2 bits becomes a compile-time register permutation (k unrolled by 4).
template<bool BN>
__global__ __launch_bounds__(256) void gemm128_k(
    const float* __restrict__ A, const float* __restrict__ W,
    const float* __restrict__ bias,
    const float* __restrict__ stIn, const float* __restrict__ gIn,
    const float* __restrict__ tIn,
    float* __restrict__ C, float* __restrict__ stOut,
    int N, float inv_n) {
    __shared__ float Wl[64 * 128];
    __shared__ float At[64 * 32];
    __shared__ float sIn[128], hIn[128];
    __shared__ float red[8 * 128];

    const int tid = threadIdx.x;
    const int cg = tid >> 3;
    const int rg = tid & 7;

    if (BN) {
        if (tid < 128) {
            float m = stIn[tid] * inv_n;
            float v = fmaxf(stIn[128 + tid] * inv_n - m * m, 0.f);
            float s = gIn[tid] * rsqrtf(v + BN_EPS);
            sIn[tid] = s;
            hIn[tid] = tIn[tid] - m * s;
        }
        __syncthreads();
    }

    const float4 breg = *(const float4*)(bias + cg * 4);
    float colS[4] = {0, 0, 0, 0}, colS2[4] = {0, 0, 0, 0};

    const int ntiles = (N + 31) >> 5;
    for (int tile = blockIdx.x; tile < ntiles; tile += gridDim.x) {
        const int r0 = tile * 32;
        float acc[4][4];
#pragma unroll
        for (int i = 0; i < 4; ++i) {
            acc[i][0] = breg.x; acc[i][1] = breg.y; acc[i][2] = breg.z; acc[i][3] = breg.w;
        }

        for (int kc = 0; kc < 2; ++kc) {
            {   // stage W chunk (64x128), straight vector copy
                const float4* Wsrc = (const float4*)W + kc * 2048;
                float4* Wd = (float4*)Wl;
#pragma unroll
                for (int i = 0; i < 8; ++i) Wd[tid + i * 256] = Wsrc[tid + i * 256];
            }
            // stage A chunk (32 rows x 64 k), BN+ReLU on the fly, swizzled store
#pragma unroll
            for (int q = 0; q < 2; ++q) {
                int f = tid + q * 256;          // 512 float4s cover the tile
                int lrow = f >> 4;              // 16 float4 per row
                int lk = (f & 15) * 4;
                int grow = r0 + lrow;
                float4 av = make_float4(0.f, 0.f, 0.f, 0.f);
                if (grow < N)
                    av = *((const float4*)(A + (size_t)grow * 128 + kc * 64 + lk));
                float vv[4] = {av.x, av.y, av.z, av.w};
#pragma unroll
                for (int j = 0; j < 4; ++j) {
                    int kk = lk + j;
                    float val = vv[j];
                    if (BN) val = fmaxf(fmaf(val, sIn[kc * 64 + kk], hIn[kc * 64 + kk]), 0.f);
                    At[kk * 32 + (lrow ^ (kk & 31))] = val;
                }
            }
            __syncthreads();

            const float4* Wl4 = (const float4*)Wl;
            const float4* At4 = (const float4*)At;
            for (int k4 = 0; k4 < 64; k4 += 4) {
#pragma unroll
                for (int u = 0; u < 4; ++u) {
                    int k = k4 + u;
                    float4 w = Wl4[k * 32 + cg];
                    float4 a = At4[k * 8 + (rg ^ ((k >> 2) & 7))];
                    float ar[4] = {a.x, a.y, a.z, a.w};
#pragma unroll
                    for (int m = 0; m < 4; ++m) {
                        float av2 = ar[m];
                        int i = m ^ u;          // compile-time (u unrolled)
                        acc[i][0] = fmaf(av2, w.x, acc[i][0]);
                        acc[i][1] = fmaf(av2, w.y, acc[i][1]);
                        acc[i][2] = fmaf(av2, w.z, acc[i][2]);
                        acc[i][3] = fmaf(av2, w.w, acc[i][3]);
                    }
                }
            }
            __syncthreads();
        }
        // epilogue: store + per-thread column stats
#pragma unroll
        for (int i = 0; i < 4; ++i) {
            int grow = r0 + rg * 4 + i;
            if (grow < N) {
                float4 o = make_float4(acc[i][0], acc[i][1], acc[i][2], acc[i][3]);
                *((float4*)(C + (size_t)grow * 128 + cg * 4)) = o;
#pragma unroll
                for (int j = 0; j < 4; ++j) {
                    colS[j] += acc[i][j];
                    colS2[j] += acc[i][j] * acc[i][j];
                }
            }
        }
    }

    // block-reduce stats over the 8 row groups, one atomic per (block, col)
    __syncthreads();
#pragma unroll
    for (int j = 0; j < 4; ++j) red[rg * 128 + cg * 4 + j] = colS[j];
    __syncthreads();
    if (rg == 0) {
#pragma unroll
        for (int j = 0; j < 4; ++j) {
            float s = 0.f;
#pragma unroll
            for (int gg = 0; gg < 8; ++gg) s += red[gg * 128 + cg * 4 + j];
            atomicAdd(stOut + cg * 4 + j, s);
        }
    }
    __syncthreads();
#pragma unroll
    for (int j = 0; j < 4; ++j) red[rg * 128 + cg * 4 + j] = colS2[j];
    __syncthreads();
    if (rg == 0) {
#pragma unroll
        for (int j = 0; j < 4; ++j) {
            float s = 0.f;
#pragma unroll
            for (int gg = 0; gg < 8; ++gg) s += red[gg * 128 + cg * 4 + j];
            atomicAdd(stOut + 128 + cg * 4 + j, s);
        }
    }
}

// ============ final: BN+ReLU -> @wf + bf -> log_softmax, wave/node ==========
__global__ void final_lsm_k(const float* __restrict__ H, const float* __restrict__ st,
                            const float* __restrict__ g, const float* __restrict__ b,
                            const float* __restrict__ wf, const float* __restrict__ bf,
                            float* __restrict__ out, int N, float inv_n) {
    int gid = blockIdx.x * blockDim.x + threadIdx.x;
    int node = gid >> 6;
    int lane = gid & 63;
    if (node >= N) return;
    int c0 = lane, c1 = lane + 64;
    float m0 = st[c0] * inv_n, m1 = st[c1] * inv_n;
    float v0 = fmaxf(st[128 + c0] * inv_n - m0 * m0, 0.f);
    float v1 = fmaxf(st[128 + c1] * inv_n - m1 * m1, 0.f);
    float s0 = g[c0] * rsqrtf(v0 + BN_EPS), s1 = g[c1] * rsqrtf(v1 + BN_EPS);
    float h0 = b[c0] - m0 * s0,            h1 = b[c1] - m1 * s1;
    const float* h = H + (size_t)node * HIDDEN;
    float a0 = fmaxf(fmaf(h[c0], s0, h0), 0.f);
    float a1 = fmaxf(fmaf(h[c1], s1, h1), 0.f);
    float logit[N_CLASS];
#pragma unroll
    for (int c = 0; c < N_CLASS; ++c) {
        float p = fmaf(a0, wf[c0 * N_CLASS + c], a1 * wf[c1 * N_CLASS + c]);
#pragma unroll
        for (int off = 32; off; off >>= 1) p += __shfl_down(p, off);
        logit[c] = p + bf[c];
    }
    if (lane == 0) {
        float m = logit[0];
#pragma unroll
        for (int c = 1; c < N_CLASS; ++c) m = fmaxf(m, logit[c]);
        float s = 0.f;
#pragma unroll
        for (int c = 0; c < N_CLASS; ++c) s += expf(logit[c] - m);
        float lse = logf(s);
#pragma unroll
        for (int c = 0; c < N_CLASS; ++c)
            out[(size_t)node * N_CLASS + c] = logit[c] - m - lse;
    }
}

// ===========================================================================

extern "C" void kernel_launch(void* const* d_in, const int* in_sizes, int n_in,
                              void* d_out, int out_size, void* d_ws, size_t ws_size,
                              hipStream_t stream) {
    const float* x   = (const float*)d_in[0];
    const float* w11 = (const float*)d_in[2];
    const float* b11 = (const float*)d_in[3];
    const float* g11 = (const float*)d_in[4];
    const float* t11 = (const float*)d_in[5];
    const float* w12 = (const float*)d_in[6];
    const float* b12 = (const float*)d_in[7];
    const float* g12 = (const float*)d_in[8];
    const float* t12 = (const float*)d_in[9];
    const float* w21 = (const float*)d_in[10];
    const float* b21 = (const float*)d_in[11];
    const float* g21 = (const float*)d_in[12];
    const float* t21 = (const float*)d_in[13];
    const float* w22 = (const float*)d_in[14];
    const float* b22 = (const float*)d_in[15];
    const float* g22 = (const float*)d_in[16];
    const float* t22 = (const float*)d_in[17];
    const float* wf  = (const float*)d_in[18];
    const float* bf  = (const float*)d_in[19];
    const int*   ei  = (const int*)d_in[20];

    const int N = in_sizes[0] / N_CLASS;      // 100000
    const int E = in_sizes[1];                // 1600000
    const float inv_n = 1.0f / (float)N;

    // ---- workspace layout ----
    float* stats = (float*)d_ws;                       // 4 x 256 floats
    float* P     = stats + 1024;                       // N*128
    float* Q     = P + (size_t)N * HIDDEN;             // N*128 (h0 aliases Q)
    float* h0    = Q;                                  // N*10, consumed before Q written
    int*   cnt     = (int*)(Q + (size_t)N * HIDDEN);   // N
    int*   row_ptr = cnt + N;                          // N
    int*   cursor  = row_ptr + N;                      // N
    int*   bsum    = cursor + N;                       // 512
    int*   col     = bsum + 512;                       // E

    const int nB = (N + 255) / 256;                    // scan blocks (391)
    const int gE = (E + 255) / 256;                    // 6250

    (void)hipMemsetAsync(stats, 0, 1024 * sizeof(float), stream);
    (void)hipMemsetAsync(cnt, 0, (size_t)N * sizeof(int), stream);

    // ---- CSR build (by dst) ----
    hist_k<<<gE, 256, 0, stream>>>(ei, cnt, E);
    scanA_k<<<nB, 256, 0, stream>>>(cnt, bsum, N);
    scanB_k<<<1, 512, 0, stream>>>(bsum, nB);
    scanC_k<<<nB, 256, 0, stream>>>(cnt, bsum, row_ptr, N);
    (void)hipMemcpyAsync(cursor, row_ptr, (size_t)N * sizeof(int),
                         hipMemcpyDeviceToDevice, stream);
    fill_k<<<gE, 256, 0, stream>>>(ei, cursor, col, E);

    // ---- layer 1 ----
    gather10_k<<<(N * N_CLASS + 255) / 256, 256, 0, stream>>>(x, col, row_ptr, cnt, h0, N);
    gemm10_k<<<512, 128, 0, stream>>>(h0, w11, b11, P, stats, N);
    gemm128_k<true><<<781, 256, 0, stream>>>(P, w12, b12, stats, g11, t11,
                                             Q, stats + 256, N, inv_n);

    // ---- layer 2 aggregation (BN2+ReLU fused into the gather) ----
    gather_bn_k<<<(N * 64 + 255) / 256, 256, 0, stream>>>(Q, col, row_ptr, cnt,
                                                          stats + 256, g12, t12, P, N, inv_n);

    // ---- layer 2 MLP ----
    gemm128_k<false><<<781, 256, 0, stream>>>(P, w21, b21, nullptr, nullptr, nullptr,
                                              Q, stats + 512, N, inv_n);
    gemm128_k<true><<<781, 256, 0, stream>>>(Q, w22, b22, stats + 512, g21, t21,
                                             P, stats + 768, N, inv_n);

    // ---- final linear + log_softmax (BN4+ReLU fused) ----
    final_lsm_k<<<(N * 64 + 255) / 256, 256, 0, stream>>>(P, stats + 768, g22, t22,
                                                          wf, bf, (float*)d_out, N, inv_n);
}

// Round 4
// 697.352 us; speedup vs baseline: 2.6722x; 1.4177x over previous
//
#include <hip/hip_runtime.h>

#define N_CLASS 10
#define HIDDEN 128
#define BN_EPS 1e-5f

typedef short short8 __attribute__((ext_vector_type(8)));   // 8 bf16 in 4 VGPRs
typedef float floatx4 __attribute__((ext_vector_type(4)));

__device__ __forceinline__ float bf2f(unsigned short u) {
    unsigned int x = ((unsigned int)u) << 16;
    float f; __builtin_memcpy(&f, &x, 4); return f;
}
__device__ __forceinline__ unsigned short f2bf(float f) {
    unsigned int x; __builtin_memcpy(&x, &f, 4);
    x += 0x7FFFu + ((x >> 16) & 1u);          // round-to-nearest-even
    return (unsigned short)(x >> 16);
}

// ============================ CSR build =====================================
__global__ void hist_k(const int* __restrict__ ei, int* __restrict__ cnt, int E) {
    int e = blockIdx.x * 256 + threadIdx.x;
    if (e < E) atomicAdd(cnt + ei[E + e], 1);
}

__global__ void scanA_k(const int* __restrict__ cnt, int* __restrict__ bsum, int N) {
    __shared__ int sm[256];
    int i = blockIdx.x * 256 + threadIdx.x;
    sm[threadIdx.x] = (i < N) ? cnt[i] : 0;
    __syncthreads();
    for (int s = 128; s > 0; s >>= 1) {
        if (threadIdx.x < s) sm[threadIdx.x] += sm[threadIdx.x + s];
        __syncthreads();
    }
    if (threadIdx.x == 0) bsum[blockIdx.x] = sm[0];
}

__global__ void scanB_k(int* __restrict__ bsum, int B) {
    __shared__ int sm[512];
    int t = threadIdx.x;
    sm[t] = (t < B) ? bsum[t] : 0;
    __syncthreads();
    for (int off = 1; off < 512; off <<= 1) {
        int u = (t >= off) ? sm[t - off] : 0;
        __syncthreads();
        sm[t] += u;
        __syncthreads();
    }
    if (t < B) bsum[t] = (t == 0) ? 0 : sm[t - 1];
}

__global__ void scanC_k(const int* __restrict__ cnt, const int* __restrict__ boff,
                        int* __restrict__ row_ptr, int N) {
    __shared__ int sm[256];
    int i = blockIdx.x * 256 + threadIdx.x;
    int t = threadIdx.x;
    int v = (i < N) ? cnt[i] : 0;
    sm[t] = v;
    __syncthreads();
    for (int off = 1; off < 256; off <<= 1) {
        int u = (t >= off) ? sm[t - off] : 0;
        __syncthreads();
        sm[t] += u;
        __syncthreads();
    }
    if (i < N) row_ptr[i] = boff[blockIdx.x] + sm[t] - v;
}

__global__ void fill_k(const int* __restrict__ ei, int* __restrict__ cursor,
                       int* __restrict__ col, int E) {
    int e = blockIdx.x * 256 + threadIdx.x;
    if (e < E) {
        int p = atomicAdd(cursor + ei[E + e], 1);
        col[p] = ei[e];
    }
}

// =================== W[k][n] fp32 -> Wt[n][k] bf16 ==========================
__global__ void prepw_k(const float* __restrict__ W, unsigned short* __restrict__ Wt) {
    int i = blockIdx.x * 256 + threadIdx.x;
    if (i < 128 * 128) {
        int k = i >> 7, n = i & 127;
        Wt[n * 128 + k] = f2bf(W[k * 128 + n]);
    }
}

// ===================== layer-1 gather: h0 = x + sum x[src] ==================
__global__ void gather10_k(const float* __restrict__ X, const int* __restrict__ col,
                           const int* __restrict__ rp, const int* __restrict__ cnt,
                           float* __restrict__ out, int N) {
    int t = blockIdx.x * 256 + threadIdx.x;
    int node = t / N_CLASS, f = t - node * N_CLASS;
    if (node >= N) return;
    int start = rp[node], deg = cnt[node];
    float acc = X[(size_t)node * N_CLASS + f];
    for (int j = 0; j < deg; ++j)
        acc += X[(size_t)col[start + j] * N_CLASS + f];
    out[(size_t)node * N_CLASS + f] = acc;
}

// ===== layer-2 gather, bf16 features, fused BN+ReLU on every element ========
__global__ __launch_bounds__(256) void gather_bn_k(
    const unsigned short* __restrict__ X, const int* __restrict__ col,
    const int* __restrict__ rp, const int* __restrict__ cnt,
    const float* __restrict__ st, const float* __restrict__ g,
    const float* __restrict__ b, unsigned short* __restrict__ out,
    int N, float inv_n) {
    int wave = (blockIdx.x * 256 + threadIdx.x) >> 6;
    int lane = threadIdx.x & 63;
    if (wave >= N) return;
    int c0 = lane * 2;
    float m0 = st[c0] * inv_n,      m1 = st[c0 + 1] * inv_n;
    float v0 = fmaxf(st[128 + c0] * inv_n - m0 * m0, 0.f);
    float v1 = fmaxf(st[128 + c0 + 1] * inv_n - m1 * m1, 0.f);
    float s0 = g[c0] * rsqrtf(v0 + BN_EPS), s1 = g[c0 + 1] * rsqrtf(v1 + BN_EPS);
    float h0 = b[c0] - m0 * s0,            h1 = b[c0 + 1] - m1 * s1;
    int start = rp[wave], deg = cnt[wave];
    const unsigned int* Xv = (const unsigned int*)X;   // 2 bf16 per uint
    unsigned int self = Xv[(size_t)wave * 64 + lane];
    float a0 = fmaxf(fmaf(bf2f(self & 0xffffu), s0, h0), 0.f);
    float a1 = fmaxf(fmaf(bf2f(self >> 16),    s1, h1), 0.f);
    for (int j = 0; j < deg; ++j) {
        int s = col[start + j];
        unsigned int v = Xv[(size_t)s * 64 + lane];
        a0 += fmaxf(fmaf(bf2f(v & 0xffffu), s0, h0), 0.f);
        a1 += fmaxf(fmaf(bf2f(v >> 16),    s1, h1), 0.f);
    }
    unsigned int o = (unsigned int)f2bf(a0) | ((unsigned int)f2bf(a1) << 16);
    ((unsigned int*)out)[(size_t)wave * 64 + lane] = o;
}

// ======== K=10 GEMM + bias + fp32 column-stats, bf16 output =================
__global__ __launch_bounds__(128) void gemm10_k(
    const float* __restrict__ A, const float* __restrict__ W,
    const float* __restrict__ bias, unsigned short* __restrict__ C,
    float* __restrict__ stOut, int N) {
    __shared__ float rb[16 * N_CLASS];
    const int tid = threadIdx.x;
    float wreg[N_CLASS];
#pragma unroll
    for (int k = 0; k < N_CLASS; ++k) wreg[k] = W[k * HIDDEN + tid];
    float bb = bias[tid];
    float s = 0.f, s2 = 0.f;
    for (int r0 = blockIdx.x * 16; r0 < N; r0 += gridDim.x * 16) {
        int nr = min(16, N - r0);
        for (int i = tid; i < nr * N_CLASS; i += 128) rb[i] = A[r0 * N_CLASS + i];
        __syncthreads();
        for (int r = 0; r < nr; ++r) {
            float acc = bb;
#pragma unroll
            for (int k = 0; k < N_CLASS; ++k) acc = fmaf(rb[r * N_CLASS + k], wreg[k], acc);
            C[(size_t)(r0 + r) * HIDDEN + tid] = f2bf(acc);
            s += acc; s2 += acc * acc;
        }
        __syncthreads();
    }
    atomicAdd(stOut + tid, s);
    atomicAdd(stOut + HIDDEN + tid, s2);
}

// ============ MFMA bf16 GEMM: Zout = [bnrelu](Zin) @ W + bias ===============
// 256 threads = 4 waves; 64-row x 128-col tile per iteration; K=128.
// Wt[n][k] bf16 pre-transposed. 16x16x32 MFMA, verified layouts (m89/m91):
//   A: m=lane&15, k=(lane>>4)*8+j   B: n=lane&15, k=(lane>>4)*8+j
//   C: col=lane&15, row=(lane>>4)*4+reg
// LDS row stride 136 bf16 (272 B) -> b128 reads are <=2-way conflicts (free).
template<bool BN>
__global__ __launch_bounds__(256) void gemm_mfma_k(
    const unsigned short* __restrict__ Zin, const unsigned short* __restrict__ Wt,
    const float* __restrict__ bias,
    const float* __restrict__ stIn, const float* __restrict__ gIn,
    const float* __restrict__ tIn,
    unsigned short* __restrict__ Zout, float* __restrict__ stOut,
    int N, float inv_n) {
    __shared__ unsigned short Wl[128 * 136];    // 34.8 KB
    __shared__ unsigned short Al[64 * 136];     // 17.4 KB (reused for C out)
    __shared__ float sTab[128], hTab[128], biasTab[128];
    __shared__ float redS[128], redS2[128];

    const int tid  = threadIdx.x;
    const int wv   = tid >> 6;
    const int ln   = tid & 63;
    const int half = ln >> 4;
    const int l16  = ln & 15;

    if (tid < 128) {
        biasTab[tid] = bias[tid];
        if (BN) {
            float m = stIn[tid] * inv_n;
            float v = fmaxf(stIn[128 + tid] * inv_n - m * m, 0.f);
            float s = gIn[tid] * rsqrtf(v + BN_EPS);
            sTab[tid] = s;
            hTab[tid] = tIn[tid] - m * s;
        }
        redS[tid] = 0.f; redS2[tid] = 0.f;
    }
    // stage Wt into LDS (row stride 136)
    for (int c = tid; c < 2048; c += 256) {
        int n = c >> 4, k8 = c & 15;
        uint4 v = *(const uint4*)(Wt + (size_t)n * 128 + k8 * 8);
        *(uint4*)(&Wl[n * 136 + k8 * 8]) = v;
    }
    __syncthreads();

    float cs[8], cs2[8];
#pragma unroll
    for (int i = 0; i < 8; ++i) { cs[i] = 0.f; cs2[i] = 0.f; }

    const int ntiles = (N + 63) >> 6;
    for (int tile = blockIdx.x; tile < ntiles; tile += gridDim.x) {
        const int r0 = tile * 64;
        // ---- stage A (64 x 128 bf16), optional BN+ReLU ----
        for (int c = tid; c < 1024; c += 256) {
            int r = c >> 4, k8 = c & 15;
            int gr = r0 + r; if (gr >= N) gr = N - 1;   // clamp; garbage rows unused
            uint4 v = *(const uint4*)(Zin + (size_t)gr * 128 + k8 * 8);
            if (BN) {
                unsigned short* us = (unsigned short*)&v;
                int kb = k8 * 8;
#pragma unroll
                for (int j = 0; j < 8; ++j) {
                    float f = fmaxf(fmaf(bf2f(us[j]), sTab[kb + j], hTab[kb + j]), 0.f);
                    us[j] = f2bf(f);
                }
            }
            *(uint4*)(&Al[r * 136 + k8 * 8]) = v;
        }
        __syncthreads();

        // ---- preload A fragments (wave wv owns rows wv*16..+15) ----
        short8 afrag[4];
        const int arow = wv * 16 + l16;
#pragma unroll
        for (int s = 0; s < 4; ++s)
            afrag[s] = *(const short8*)(&Al[arow * 136 + s * 32 + half * 8]);
        __syncthreads();   // Al now reusable as C buffer

        // ---- 8 col-tiles x 4 K-steps ----
#pragma unroll
        for (int ct = 0; ct < 8; ++ct) {
            floatx4 acc = {0.f, 0.f, 0.f, 0.f};
            const int bn_ = ct * 16 + l16;
#pragma unroll
            for (int s = 0; s < 4; ++s) {
                short8 bfrag = *(const short8*)(&Wl[bn_ * 136 + s * 32 + half * 8]);
                acc = __builtin_amdgcn_mfma_f32_16x16x32_bf16(afrag[s], bfrag, acc, 0, 0, 0);
            }
            float bcol = biasTab[bn_];
#pragma unroll
            for (int r = 0; r < 4; ++r) {
                int lrow = wv * 16 + half * 4 + r;
                float val = acc[r] + bcol;
                if (r0 + lrow < N) { cs[ct] += val; cs2[ct] += val * val; }
                Al[lrow * 136 + bn_] = f2bf(val);
            }
        }
        __syncthreads();

        // ---- coalesced C writeback ----
        for (int c = tid; c < 1024; c += 256) {
            int r = c >> 4, k8 = c & 15;
            int gr = r0 + r;
            if (gr < N)
                *(uint4*)(Zout + (size_t)gr * 128 + k8 * 8) = *(const uint4*)(&Al[r * 136 + k8 * 8]);
        }
        __syncthreads();
    }

    // ---- stats reduction: quads of a wave hold same col -> shuffle, LDS, global
#pragma unroll
    for (int ct = 0; ct < 8; ++ct) {
        float a = cs[ct], b = cs2[ct];
        a += __shfl_xor(a, 16); a += __shfl_xor(a, 32);
        b += __shfl_xor(b, 16); b += __shfl_xor(b, 32);
        if (half == 0) {
            atomicAdd(&redS[ct * 16 + l16], a);
            atomicAdd(&redS2[ct * 16 + l16], b);
        }
    }
    __syncthreads();
    if (tid < 128) {
        atomicAdd(stOut + tid, redS[tid]);
        atomicAdd(stOut + 128 + tid, redS2[tid]);
    }
}

// ====== final: BN+ReLU -> @wf + bf -> log_softmax, one wave per node ========
__global__ void final_lsm_k(const unsigned short* __restrict__ H, const float* __restrict__ st,
                            const float* __restrict__ g, const float* __restrict__ b,
                            const float* __restrict__ wf, const float* __restrict__ bf,
                            float* __restrict__ out, int N, float inv_n) {
    int gid = blockIdx.x * blockDim.x + threadIdx.x;
    int node = gid >> 6;
    int lane = gid & 63;
    if (node >= N) return;
    int c0 = lane, c1 = lane + 64;
    float m0 = st[c0] * inv_n, m1 = st[c1] * inv_n;
    float v0 = fmaxf(st[128 + c0] * inv_n - m0 * m0, 0.f);
    float v1 = fmaxf(st[128 + c1] * inv_n - m1 * m1, 0.f);
    float s0 = g[c0] * rsqrtf(v0 + BN_EPS), s1 = g[c1] * rsqrtf(v1 + BN_EPS);
    float h0 = b[c0] - m0 * s0,            h1 = b[c1] - m1 * s1;
    const unsigned short* h = H + (size_t)node * HIDDEN;
    float a0 = fmaxf(fmaf(bf2f(h[c0]), s0, h0), 0.f);
    float a1 = fmaxf(fmaf(bf2f(h[c1]), s1, h1), 0.f);
    float logit[N_CLASS];
#pragma unroll
    for (int c = 0; c < N_CLASS; ++c) {
        float p = fmaf(a0, wf[c0 * N_CLASS + c], a1 * wf[c1 * N_CLASS + c]);
#pragma unroll
        for (int off = 32; off; off >>= 1) p += __shfl_down(p, off);
        logit[c] = p + bf[c];
    }
    if (lane == 0) {
        float m = logit[0];
#pragma unroll
        for (int c = 1; c < N_CLASS; ++c) m = fmaxf(m, logit[c]);
        float s = 0.f;
#pragma unroll
        for (int c = 0; c < N_CLASS; ++c) s += expf(logit[c] - m);
        float lse = logf(s);
#pragma unroll
        for (int c = 0; c < N_CLASS; ++c)
            out[(size_t)node * N_CLASS + c] = logit[c] - m - lse;
    }
}

// ===========================================================================

extern "C" void kernel_launch(void* const* d_in, const int* in_sizes, int n_in,
                              void* d_out, int out_size, void* d_ws, size_t ws_size,
                              hipStream_t stream) {
    const float* x   = (const float*)d_in[0];
    const float* w11 = (const float*)d_in[2];
    const float* b11 = (const float*)d_in[3];
    const float* g11 = (const float*)d_in[4];
    const float* t11 = (const float*)d_in[5];
    const float* w12 = (const float*)d_in[6];
    const float* b12 = (const float*)d_in[7];
    const float* g12 = (const float*)d_in[8];
    const float* t12 = (const float*)d_in[9];
    const float* w21 = (const float*)d_in[10];
    const float* b21 = (const float*)d_in[11];
    const float* g21 = (const float*)d_in[12];
    const float* t21 = (const float*)d_in[13];
    const float* w22 = (const float*)d_in[14];
    const float* b22 = (const float*)d_in[15];
    const float* g22 = (const float*)d_in[16];
    const float* t22 = (const float*)d_in[17];
    const float* wf  = (const float*)d_in[18];
    const float* bf  = (const float*)d_in[19];
    const int*   ei  = (const int*)d_in[20];

    const int N = in_sizes[0] / N_CLASS;      // 100000
    const int E = in_sizes[1];                // 1600000
    const float inv_n = 1.0f / (float)N;

    // ---- workspace layout (16B-aligned sections) ----
    char* base = (char*)d_ws;
    size_t off = 0;
    auto take = [&](size_t bytes) { void* p = base + off; off += (bytes + 15) & ~(size_t)15; return p; };
    float*          stats   = (float*)take(1024 * 4);
    float*          h0      = (float*)take((size_t)N * N_CLASS * 4);
    int*            cnt     = (int*)take((size_t)N * 4);
    int*            row_ptr = (int*)take((size_t)N * 4);
    int*            cursor  = (int*)take((size_t)N * 4);
    int*            bsum    = (int*)take(512 * 4);
    int*            col     = (int*)take((size_t)E * 4);
    unsigned short* bufA    = (unsigned short*)take((size_t)N * HIDDEN * 2);
    unsigned short* bufB    = (unsigned short*)take((size_t)N * HIDDEN * 2);
    unsigned short* Wt1     = (unsigned short*)take(128 * 128 * 2);
    unsigned short* Wt2     = (unsigned short*)take(128 * 128 * 2);
    unsigned short* Wt3     = (unsigned short*)take(128 * 128 * 2);

    const int nB = (N + 255) / 256;
    const int gE = (E + 255) / 256;

    (void)hipMemsetAsync(stats, 0, 1024 * sizeof(float), stream);
    (void)hipMemsetAsync(cnt, 0, (size_t)N * sizeof(int), stream);

    // ---- weight prep (bf16, transposed) ----
    prepw_k<<<64, 256, 0, stream>>>(w12, Wt1);
    prepw_k<<<64, 256, 0, stream>>>(w21, Wt2);
    prepw_k<<<64, 256, 0, stream>>>(w22, Wt3);

    // ---- CSR build (by dst) ----
    hist_k<<<gE, 256, 0, stream>>>(ei, cnt, E);
    scanA_k<<<nB, 256, 0, stream>>>(cnt, bsum, N);
    scanB_k<<<1, 512, 0, stream>>>(bsum, nB);
    scanC_k<<<nB, 256, 0, stream>>>(cnt, bsum, row_ptr, N);
    (void)hipMemcpyAsync(cursor, row_ptr, (size_t)N * sizeof(int),
                         hipMemcpyDeviceToDevice, stream);
    fill_k<<<gE, 256, 0, stream>>>(ei, cursor, col, E);

    // ---- layer 1 ----
    gather10_k<<<(N * N_CLASS + 255) / 256, 256, 0, stream>>>(x, col, row_ptr, cnt, h0, N);
    gemm10_k<<<512, 128, 0, stream>>>(h0, w11, b11, bufA, stats, N);            // Z1 + stats0
    gemm_mfma_k<true><<<512, 256, 0, stream>>>(bufA, Wt1, b12, stats, g11, t11,
                                               bufB, stats + 256, N, inv_n);    // Z2 + stats1

    // ---- layer 2 aggregation (BN2+ReLU fused) ----
    gather_bn_k<<<(N * 64 + 255) / 256, 256, 0, stream>>>(bufB, col, row_ptr, cnt,
                                                          stats + 256, g12, t12, bufA, N, inv_n);

    // ---- layer 2 MLP ----
    gemm_mfma_k<false><<<512, 256, 0, stream>>>(bufA, Wt2, b21, nullptr, nullptr, nullptr,
                                                bufB, stats + 512, N, inv_n);   // Z3 + stats2
    gemm_mfma_k<true><<<512, 256, 0, stream>>>(bufB, Wt3, b22, stats + 512, g21, t21,
                                               bufA, stats + 768, N, inv_n);    // Z4 + stats3

    // ---- final linear + log_softmax (BN4+ReLU fused) ----
    final_lsm_k<<<(N * 64 + 255) / 256, 256, 0, stream>>>(bufA, stats + 768, g22, t22,
                                                          wf, bf, (float*)d_out, N, inv_n);
}

// Round 5
// 599.825 us; speedup vs baseline: 3.1067x; 1.1626x over previous
//
#include <hip/hip_runtime.h>

#define N_CLASS 10
#define HIDDEN 128
#define BN_EPS 1e-5f

typedef short short8 __attribute__((ext_vector_type(8)));   // 8 bf16 in 4 VGPRs
typedef float floatx4 __attribute__((ext_vector_type(4)));

__device__ __forceinline__ float bf2f(unsigned short u) {
    unsigned int x = ((unsigned int)u) << 16;
    float f; __builtin_memcpy(&f, &x, 4); return f;
}
__device__ __forceinline__ unsigned short f2bf(float f) {
    unsigned int x; __builtin_memcpy(&x, &f, 4);
    x += 0x7FFFu + ((x >> 16) & 1u);          // round-to-nearest-even
    return (unsigned short)(x >> 16);
}

// ============================ CSR build =====================================
__global__ void hist_k(const int* __restrict__ ei, int* __restrict__ cnt, int E) {
    int e = blockIdx.x * 256 + threadIdx.x;
    if (e < E) atomicAdd(cnt + ei[E + e], 1);
}

__global__ void scanA_k(const int* __restrict__ cnt, int* __restrict__ bsum, int N) {
    __shared__ int sm[256];
    int i = blockIdx.x * 256 + threadIdx.x;
    sm[threadIdx.x] = (i < N) ? cnt[i] : 0;
    __syncthreads();
    for (int s = 128; s > 0; s >>= 1) {
        if (threadIdx.x < s) sm[threadIdx.x] += sm[threadIdx.x + s];
        __syncthreads();
    }
    if (threadIdx.x == 0) bsum[blockIdx.x] = sm[0];
}

__global__ void scanB_k(int* __restrict__ bsum, int B) {
    __shared__ int sm[512];
    int t = threadIdx.x;
    sm[t] = (t < B) ? bsum[t] : 0;
    __syncthreads();
    for (int off = 1; off < 512; off <<= 1) {
        int u = (t >= off) ? sm[t - off] : 0;
        __syncthreads();
        sm[t] += u;
        __syncthreads();
    }
    if (t < B) bsum[t] = (t == 0) ? 0 : sm[t - 1];
}

__global__ void scanC_k(const int* __restrict__ cnt, const int* __restrict__ boff,
                        int* __restrict__ row_ptr, int N) {
    __shared__ int sm[256];
    int i = blockIdx.x * 256 + threadIdx.x;
    int t = threadIdx.x;
    int v = (i < N) ? cnt[i] : 0;
    sm[t] = v;
    __syncthreads();
    for (int off = 1; off < 256; off <<= 1) {
        int u = (t >= off) ? sm[t - off] : 0;
        __syncthreads();
        sm[t] += u;
        __syncthreads();
    }
    if (i < N) row_ptr[i] = boff[blockIdx.x] + sm[t] - v;
}

__global__ void fill_k(const int* __restrict__ ei, int* __restrict__ cursor,
                       int* __restrict__ col, int E) {
    int e = blockIdx.x * 256 + threadIdx.x;
    if (e < E) {
        int p = atomicAdd(cursor + ei[E + e], 1);
        col[p] = ei[e];
    }
}

// =================== W[k][n] fp32 -> Wt[n][k] bf16 ==========================
__global__ void prepw_k(const float* __restrict__ W, unsigned short* __restrict__ Wt) {
    int i = blockIdx.x * 256 + threadIdx.x;
    if (i < 128 * 128) {
        int k = i >> 7, n = i & 127;
        Wt[n * 128 + k] = f2bf(W[k * 128 + n]);
    }
}

// ===================== layer-1 gather: h0 = x + sum x[src] ==================
// 4x unrolled: 4 independent row loads in flight per iteration.
__global__ void gather10_k(const float* __restrict__ X, const int* __restrict__ col,
                           const int* __restrict__ rp, const int* __restrict__ cnt,
                           float* __restrict__ out, int N) {
    int t = blockIdx.x * 256 + threadIdx.x;
    int node = t / N_CLASS, f = t - node * N_CLASS;
    if (node >= N) return;
    int start = rp[node], deg = cnt[node];
    float acc = X[(size_t)node * N_CLASS + f];
    int j = 0;
    for (; j + 4 <= deg; j += 4) {
        int s0 = col[start + j];
        int s1 = col[start + j + 1];
        int s2 = col[start + j + 2];
        int s3 = col[start + j + 3];
        float v0 = X[(size_t)s0 * N_CLASS + f];
        float v1 = X[(size_t)s1 * N_CLASS + f];
        float v2 = X[(size_t)s2 * N_CLASS + f];
        float v3 = X[(size_t)s3 * N_CLASS + f];
        acc += v0; acc += v1; acc += v2; acc += v3;
    }
    for (; j < deg; ++j)
        acc += X[(size_t)col[start + j] * N_CLASS + f];
    out[(size_t)node * N_CLASS + f] = acc;
}

// ===== layer-2 gather, bf16 features, fused BN+ReLU, 4x-unrolled loads ======
__global__ __launch_bounds__(256) void gather_bn_k(
    const unsigned short* __restrict__ X, const int* __restrict__ col,
    const int* __restrict__ rp, const int* __restrict__ cnt,
    const float* __restrict__ st, const float* __restrict__ g,
    const float* __restrict__ b, unsigned short* __restrict__ out,
    int N, float inv_n) {
    int wave = (blockIdx.x * 256 + threadIdx.x) >> 6;
    int lane = threadIdx.x & 63;
    if (wave >= N) return;
    int c0 = lane * 2;
    float m0 = st[c0] * inv_n,      m1 = st[c0 + 1] * inv_n;
    float v0_ = fmaxf(st[128 + c0] * inv_n - m0 * m0, 0.f);
    float v1_ = fmaxf(st[128 + c0 + 1] * inv_n - m1 * m1, 0.f);
    float s0 = g[c0] * rsqrtf(v0_ + BN_EPS), s1 = g[c0 + 1] * rsqrtf(v1_ + BN_EPS);
    float h0 = b[c0] - m0 * s0,             h1 = b[c0 + 1] - m1 * s1;
    int start = rp[wave], deg = cnt[wave];
    const unsigned int* Xv = (const unsigned int*)X;   // 2 bf16 per uint
    unsigned int self = Xv[(size_t)wave * 64 + lane];
    float a0 = fmaxf(fmaf(bf2f(self & 0xffffu), s0, h0), 0.f);
    float a1 = fmaxf(fmaf(bf2f(self >> 16),    s1, h1), 0.f);
    int j = 0;
    for (; j + 4 <= deg; j += 4) {
        int n0 = col[start + j];
        int n1 = col[start + j + 1];
        int n2 = col[start + j + 2];
        int n3 = col[start + j + 3];
        unsigned int w0 = Xv[(size_t)n0 * 64 + lane];
        unsigned int w1 = Xv[(size_t)n1 * 64 + lane];
        unsigned int w2 = Xv[(size_t)n2 * 64 + lane];
        unsigned int w3 = Xv[(size_t)n3 * 64 + lane];
        a0 += fmaxf(fmaf(bf2f(w0 & 0xffffu), s0, h0), 0.f);
        a1 += fmaxf(fmaf(bf2f(w0 >> 16),    s1, h1), 0.f);
        a0 += fmaxf(fmaf(bf2f(w1 & 0xffffu), s0, h0), 0.f);
        a1 += fmaxf(fmaf(bf2f(w1 >> 16),    s1, h1), 0.f);
        a0 += fmaxf(fmaf(bf2f(w2 & 0xffffu), s0, h0), 0.f);
        a1 += fmaxf(fmaf(bf2f(w2 >> 16),    s1, h1), 0.f);
        a0 += fmaxf(fmaf(bf2f(w3 & 0xffffu), s0, h0), 0.f);
        a1 += fmaxf(fmaf(bf2f(w3 >> 16),    s1, h1), 0.f);
    }
    for (; j < deg; ++j) {
        int s = col[start + j];
        unsigned int v = Xv[(size_t)s * 64 + lane];
        a0 += fmaxf(fmaf(bf2f(v & 0xffffu), s0, h0), 0.f);
        a1 += fmaxf(fmaf(bf2f(v >> 16),    s1, h1), 0.f);
    }
    unsigned int o = (unsigned int)f2bf(a0) | ((unsigned int)f2bf(a1) << 16);
    ((unsigned int*)out)[(size_t)wave * 64 + lane] = o;
}

// ======== K=10 GEMM + bias + fp32 column-stats, bf16 output =================
__global__ __launch_bounds__(128) void gemm10_k(
    const float* __restrict__ A, const float* __restrict__ W,
    const float* __restrict__ bias, unsigned short* __restrict__ C,
    float* __restrict__ stOut, int N) {
    __shared__ float rb[16 * N_CLASS];
    const int tid = threadIdx.x;
    float wreg[N_CLASS];
#pragma unroll
    for (int k = 0; k < N_CLASS; ++k) wreg[k] = W[k * HIDDEN + tid];
    float bb = bias[tid];
    float s = 0.f, s2 = 0.f;
    for (int r0 = blockIdx.x * 16; r0 < N; r0 += gridDim.x * 16) {
        int nr = min(16, N - r0);
        for (int i = tid; i < nr * N_CLASS; i += 128) rb[i] = A[r0 * N_CLASS + i];
        __syncthreads();
        for (int r = 0; r < nr; ++r) {
            float acc = bb;
#pragma unroll
            for (int k = 0; k < N_CLASS; ++k) acc = fmaf(rb[r * N_CLASS + k], wreg[k], acc);
            C[(size_t)(r0 + r) * HIDDEN + tid] = f2bf(acc);
            s += acc; s2 += acc * acc;
        }
        __syncthreads();
    }
    atomicAdd(stOut + tid, s);
    atomicAdd(stOut + HIDDEN + tid, s2);
}

// ============ MFMA bf16 GEMM: Zout = [bnrelu](Zin) @ W + bias ===============
// 256 threads = 4 waves; 64-row x 128-col tile per iteration; K=128.
// Wt[n][k] bf16 pre-transposed. 16x16x32 MFMA, verified layouts (m89/m91):
//   A: m=lane&15, k=(lane>>4)*8+j   B: n=lane&15, k=(lane>>4)*8+j
//   C: col=lane&15, row=(lane>>4)*4+reg
// LDS row stride 136 bf16 (272 B) -> b128 reads are <=2-way conflicts (free).
template<bool BN>
__global__ __launch_bounds__(256) void gemm_mfma_k(
    const unsigned short* __restrict__ Zin, const unsigned short* __restrict__ Wt,
    const float* __restrict__ bias,
    const float* __restrict__ stIn, const float* __restrict__ gIn,
    const float* __restrict__ tIn,
    unsigned short* __restrict__ Zout, float* __restrict__ stOut,
    int N, float inv_n) {
    __shared__ unsigned short Wl[128 * 136];    // 34.8 KB
    __shared__ unsigned short Al[64 * 136];     // 17.4 KB (reused for C out)
    __shared__ float sTab[128], hTab[128], biasTab[128];
    __shared__ float redS[128], redS2[128];

    const int tid  = threadIdx.x;
    const int wv   = tid >> 6;
    const int ln   = tid & 63;
    const int half = ln >> 4;
    const int l16  = ln & 15;

    if (tid < 128) {
        biasTab[tid] = bias[tid];
        if (BN) {
            float m = stIn[tid] * inv_n;
            float v = fmaxf(stIn[128 + tid] * inv_n - m * m, 0.f);
            float s = gIn[tid] * rsqrtf(v + BN_EPS);
            sTab[tid] = s;
            hTab[tid] = tIn[tid] - m * s;
        }
        redS[tid] = 0.f; redS2[tid] = 0.f;
    }
    // stage Wt into LDS (row stride 136)
    for (int c = tid; c < 2048; c += 256) {
        int n = c >> 4, k8 = c & 15;
        uint4 v = *(const uint4*)(Wt + (size_t)n * 128 + k8 * 8);
        *(uint4*)(&Wl[n * 136 + k8 * 8]) = v;
    }
    __syncthreads();

    float cs[8], cs2[8];
#pragma unroll
    for (int i = 0; i < 8; ++i) { cs[i] = 0.f; cs2[i] = 0.f; }

    const int ntiles = (N + 63) >> 6;
    for (int tile = blockIdx.x; tile < ntiles; tile += gridDim.x) {
        const int r0 = tile * 64;
        // ---- stage A (64 x 128 bf16), optional BN+ReLU ----
        for (int c = tid; c < 1024; c += 256) {
            int r = c >> 4, k8 = c & 15;
            int gr = r0 + r; if (gr >= N) gr = N - 1;   // clamp; garbage rows unused
            uint4 v = *(const uint4*)(Zin + (size_t)gr * 128 + k8 * 8);
            if (BN) {
                unsigned short* us = (unsigned short*)&v;
                int kb = k8 * 8;
#pragma unroll
                for (int j = 0; j < 8; ++j) {
                    float f = fmaxf(fmaf(bf2f(us[j]), sTab[kb + j], hTab[kb + j]), 0.f);
                    us[j] = f2bf(f);
                }
            }
            *(uint4*)(&Al[r * 136 + k8 * 8]) = v;
        }
        __syncthreads();

        // ---- preload A fragments (wave wv owns rows wv*16..+15) ----
        short8 afrag[4];
        const int arow = wv * 16 + l16;
#pragma unroll
        for (int s = 0; s < 4; ++s)
            afrag[s] = *(const short8*)(&Al[arow * 136 + s * 32 + half * 8]);
        __syncthreads();   // Al now reusable as C buffer

        // ---- 8 col-tiles x 4 K-steps ----
#pragma unroll
        for (int ct = 0; ct < 8; ++ct) {
            floatx4 acc = {0.f, 0.f, 0.f, 0.f};
            const int bn_ = ct * 16 + l16;
#pragma unroll
            for (int s = 0; s < 4; ++s) {
                short8 bfrag = *(const short8*)(&Wl[bn_ * 136 + s * 32 + half * 8]);
                acc = __builtin_amdgcn_mfma_f32_16x16x32_bf16(afrag[s], bfrag, acc, 0, 0, 0);
            }
            float bcol = biasTab[bn_];
#pragma unroll
            for (int r = 0; r < 4; ++r) {
                int lrow = wv * 16 + half * 4 + r;
                float val = acc[r] + bcol;
                if (r0 + lrow < N) { cs[ct] += val; cs2[ct] += val * val; }
                Al[lrow * 136 + bn_] = f2bf(val);
            }
        }
        __syncthreads();

        // ---- coalesced C writeback ----
        for (int c = tid; c < 1024; c += 256) {
            int r = c >> 4, k8 = c & 15;
            int gr = r0 + r;
            if (gr < N)
                *(uint4*)(Zout + (size_t)gr * 128 + k8 * 8) = *(const uint4*)(&Al[r * 136 + k8 * 8]);
        }
        __syncthreads();
    }

    // ---- stats reduction: quads of a wave hold same col -> shuffle, LDS, global
#pragma unroll
    for (int ct = 0; ct < 8; ++ct) {
        float a = cs[ct], b = cs2[ct];
        a += __shfl_xor(a, 16); a += __shfl_xor(a, 32);
        b += __shfl_xor(b, 16); b += __shfl_xor(b, 32);
        if (half == 0) {
            atomicAdd(&redS[ct * 16 + l16], a);
            atomicAdd(&redS2[ct * 16 + l16], b);
        }
    }
    __syncthreads();
    if (tid < 128) {
        atomicAdd(stOut + tid, redS[tid]);
        atomicAdd(stOut + 128 + tid, redS2[tid]);
    }
}

// ====== final: BN+ReLU -> @wf + bf -> log_softmax, one wave per node ========
__global__ void final_lsm_k(const unsigned short* __restrict__ H, const float* __restrict__ st,
                            const float* __restrict__ g, const float* __restrict__ b,
                            const float* __restrict__ wf, const float* __restrict__ bf,
                            float* __restrict__ out, int N, float inv_n) {
    int gid = blockIdx.x * blockDim.x + threadIdx.x;
    int node = gid >> 6;
    int lane = gid & 63;
    if (node >= N) return;
    int c0 = lane, c1 = lane + 64;
    float m0 = st[c0] * inv_n, m1 = st[c1] * inv_n;
    float v0 = fmaxf(st[128 + c0] * inv_n - m0 * m0, 0.f);
    float v1 = fmaxf(st[128 + c1] * inv_n - m1 * m1, 0.f);
    float s0 = g[c0] * rsqrtf(v0 + BN_EPS), s1 = g[c1] * rsqrtf(v1 + BN_EPS);
    float h0 = b[c0] - m0 * s0,            h1 = b[c1] - m1 * s1;
    const unsigned short* h = H + (size_t)node * HIDDEN;
    float a0 = fmaxf(fmaf(bf2f(h[c0]), s0, h0), 0.f);
    float a1 = fmaxf(fmaf(bf2f(h[c1]), s1, h1), 0.f);
    float logit[N_CLASS];
#pragma unroll
    for (int c = 0; c < N_CLASS; ++c) {
        float p = fmaf(a0, wf[c0 * N_CLASS + c], a1 * wf[c1 * N_CLASS + c]);
#pragma unroll
        for (int off = 32; off; off >>= 1) p += __shfl_down(p, off);
        logit[c] = p + bf[c];
    }
    if (lane == 0) {
        float m = logit[0];
#pragma unroll
        for (int c = 1; c < N_CLASS; ++c) m = fmaxf(m, logit[c]);
        float s = 0.f;
#pragma unroll
        for (int c = 0; c < N_CLASS; ++c) s += expf(logit[c] - m);
        float lse = logf(s);
#pragma unroll
        for (int c = 0; c < N_CLASS; ++c)
            out[(size_t)node * N_CLASS + c] = logit[c] - m - lse;
    }
}

// ===========================================================================

extern "C" void kernel_launch(void* const* d_in, const int* in_sizes, int n_in,
                              void* d_out, int out_size, void* d_ws, size_t ws_size,
                              hipStream_t stream) {
    const float* x   = (const float*)d_in[0];
    const float* w11 = (const float*)d_in[2];
    const float* b11 = (const float*)d_in[3];
    const float* g11 = (const float*)d_in[4];
    const float* t11 = (const float*)d_in[5];
    const float* w12 = (const float*)d_in[6];
    const float* b12 = (const float*)d_in[7];
    const float* g12 = (const float*)d_in[8];
    const float* t12 = (const float*)d_in[9];
    const float* w21 = (const float*)d_in[10];
    const float* b21 = (const float*)d_in[11];
    const float* g21 = (const float*)d_in[12];
    const float* t21 = (const float*)d_in[13];
    const float* w22 = (const float*)d_in[14];
    const float* b22 = (const float*)d_in[15];
    const float* g22 = (const float*)d_in[16];
    const float* t22 = (const float*)d_in[17];
    const float* wf  = (const float*)d_in[18];
    const float* bf  = (const float*)d_in[19];
    const int*   ei  = (const int*)d_in[20];

    const int N = in_sizes[0] / N_CLASS;      // 100000
    const int E = in_sizes[1];                // 1600000
    const float inv_n = 1.0f / (float)N;

    // ---- workspace layout (16B-aligned sections) ----
    char* base = (char*)d_ws;
    size_t off = 0;
    auto take = [&](size_t bytes) { void* p = base + off; off += (bytes + 15) & ~(size_t)15; return p; };
    float*          stats   = (float*)take(1024 * 4);
    float*          h0      = (float*)take((size_t)N * N_CLASS * 4);
    int*            cnt     = (int*)take((size_t)N * 4);
    int*            row_ptr = (int*)take((size_t)N * 4);
    int*            cursor  = (int*)take((size_t)N * 4);
    int*            bsum    = (int*)take(512 * 4);
    int*            col     = (int*)take((size_t)E * 4);
    unsigned short* bufA    = (unsigned short*)take((size_t)N * HIDDEN * 2);
    unsigned short* bufB    = (unsigned short*)take((size_t)N * HIDDEN * 2);
    unsigned short* Wt1     = (unsigned short*)take(128 * 128 * 2);
    unsigned short* Wt2     = (unsigned short*)take(128 * 128 * 2);
    unsigned short* Wt3     = (unsigned short*)take(128 * 128 * 2);

    const int nB = (N + 255) / 256;
    const int gE = (E + 255) / 256;

    (void)hipMemsetAsync(stats, 0, 1024 * sizeof(float), stream);
    (void)hipMemsetAsync(cnt, 0, (size_t)N * sizeof(int), stream);

    // ---- weight prep (bf16, transposed) ----
    prepw_k<<<64, 256, 0, stream>>>(w12, Wt1);
    prepw_k<<<64, 256, 0, stream>>>(w21, Wt2);
    prepw_k<<<64, 256, 0, stream>>>(w22, Wt3);

    // ---- CSR build (by dst) ----
    hist_k<<<gE, 256, 0, stream>>>(ei, cnt, E);
    scanA_k<<<nB, 256, 0, stream>>>(cnt, bsum, N);
    scanB_k<<<1, 512, 0, stream>>>(bsum, nB);
    scanC_k<<<nB, 256, 0, stream>>>(cnt, bsum, row_ptr, N);
    (void)hipMemcpyAsync(cursor, row_ptr, (size_t)N * sizeof(int),
                         hipMemcpyDeviceToDevice, stream);
    fill_k<<<gE, 256, 0, stream>>>(ei, cursor, col, E);

    // ---- layer 1 ----
    gather10_k<<<(N * N_CLASS + 255) / 256, 256, 0, stream>>>(x, col, row_ptr, cnt, h0, N);
    gemm10_k<<<512, 128, 0, stream>>>(h0, w11, b11, bufA, stats, N);            // Z1 + stats0
    gemm_mfma_k<true><<<512, 256, 0, stream>>>(bufA, Wt1, b12, stats, g11, t11,
                                               bufB, stats + 256, N, inv_n);    // Z2 + stats1

    // ---- layer 2 aggregation (BN2+ReLU fused) ----
    gather_bn_k<<<(N * 64 + 255) / 256, 256, 0, stream>>>(bufB, col, row_ptr, cnt,
                                                          stats + 256, g12, t12, bufA, N, inv_n);

    // ---- layer 2 MLP ----
    gemm_mfma_k<false><<<512, 256, 0, stream>>>(bufA, Wt2, b21, nullptr, nullptr, nullptr,
                                                bufB, stats + 512, N, inv_n);   // Z3 + stats2
    gemm_mfma_k<true><<<512, 256, 0, stream>>>(bufB, Wt3, b22, stats + 512, g21, t21,
                                               bufA, stats + 768, N, inv_n);    // Z4 + stats3

    // ---- final linear + log_softmax (BN4+ReLU fused) ----
    final_lsm_k<<<(N * 64 + 255) / 256, 256, 0, stream>>>(bufA, stats + 768, g22, t22,
                                                          wf, bf, (float*)d_out, N, inv_n);
}

// Round 6
// 490.183 us; speedup vs baseline: 3.8016x; 1.2237x over previous
//
#include <hip/hip_runtime.h>

#define N_CLASS 10
#define HIDDEN 128
#define BN_EPS 1e-5f

typedef short short8 __attribute__((ext_vector_type(8)));   // 8 bf16 in 4 VGPRs
typedef float floatx4 __attribute__((ext_vector_type(4)));

__device__ __forceinline__ float bf2f(unsigned short u) {
    unsigned int x = ((unsigned int)u) << 16;
    float f; __builtin_memcpy(&f, &x, 4); return f;
}
__device__ __forceinline__ unsigned short f2bf(float f) {
    unsigned int x; __builtin_memcpy(&x, &f, 4);
    x += 0x7FFFu + ((x >> 16) & 1u);          // round-to-nearest-even
    return (unsigned short)(x >> 16);
}

// ============================ CSR build =====================================
// hist: per-dst degree count AND per-edge rank (slot within its dst row)
__global__ void hist_k(const int* __restrict__ ei, int* __restrict__ cnt,
                       int* __restrict__ rank, int E) {
    int e = blockIdx.x * 256 + threadIdx.x;
    if (e < E) rank[e] = atomicAdd(cnt + ei[E + e], 1);
}

__global__ void scanA_k(const int* __restrict__ cnt, int* __restrict__ bsum, int N) {
    __shared__ int sm[256];
    int i = blockIdx.x * 256 + threadIdx.x;
    sm[threadIdx.x] = (i < N) ? cnt[i] : 0;
    __syncthreads();
    for (int s = 128; s > 0; s >>= 1) {
        if (threadIdx.x < s) sm[threadIdx.x] += sm[threadIdx.x + s];
        __syncthreads();
    }
    if (threadIdx.x == 0) bsum[blockIdx.x] = sm[0];
}

__global__ void scanB_k(int* __restrict__ bsum, int B) {
    __shared__ int sm[512];
    int t = threadIdx.x;
    sm[t] = (t < B) ? bsum[t] : 0;
    __syncthreads();
    for (int off = 1; off < 512; off <<= 1) {
        int u = (t >= off) ? sm[t - off] : 0;
        __syncthreads();
        sm[t] += u;
        __syncthreads();
    }
    if (t < B) bsum[t] = (t == 0) ? 0 : sm[t - 1];
}

__global__ void scanC_k(const int* __restrict__ cnt, const int* __restrict__ boff,
                        int* __restrict__ row_ptr, int N) {
    __shared__ int sm[256];
    int i = blockIdx.x * 256 + threadIdx.x;
    int t = threadIdx.x;
    int v = (i < N) ? cnt[i] : 0;
    sm[t] = v;
    __syncthreads();
    for (int off = 1; off < 256; off <<= 1) {
        int u = (t >= off) ? sm[t - off] : 0;
        __syncthreads();
        sm[t] += u;
        __syncthreads();
    }
    if (i < N) row_ptr[i] = boff[blockIdx.x] + sm[t] - v;
}

// Atomic-free fill in P dst-range passes: each pass's col writes land in a
// ~1.6 MB window (fits per-XCD L2) so line-RMW merges before HBM writeback.
__global__ void fill_k(const int* __restrict__ ei, const int* __restrict__ rank,
                       const int* __restrict__ rp, int* __restrict__ col,
                       int E, int N) {
    const int P = 4;
    const int rs = (N + P - 1) / P;
    const int stride = gridDim.x * 256;
#pragma unroll 1
    for (int pass = 0; pass < P; ++pass) {
        int lo = pass * rs, hi = lo + rs;
        for (int e = blockIdx.x * 256 + threadIdx.x; e < E; e += stride) {
            int d = ei[E + e];
            if (d >= lo && d < hi)
                col[rp[d] + rank[e]] = ei[e];
        }
    }
}

// =================== W[k][n] fp32 -> Wt[n][k] bf16 ==========================
__global__ void prepw_k(const float* __restrict__ W, unsigned short* __restrict__ Wt) {
    int i = blockIdx.x * 256 + threadIdx.x;
    if (i < 128 * 128) {
        int k = i >> 7, n = i & 127;
        Wt[n * 128 + k] = f2bf(W[k * 128 + n]);
    }
}

// ===================== layer-1 gather: h0 = x + sum x[src] ==================
// 8x unrolled: 8 independent row loads in flight per iteration.
__global__ void gather10_k(const float* __restrict__ X, const int* __restrict__ col,
                           const int* __restrict__ rp, const int* __restrict__ cnt,
                           float* __restrict__ out, int N) {
    int t = blockIdx.x * 256 + threadIdx.x;
    int node = t / N_CLASS, f = t - node * N_CLASS;
    if (node >= N) return;
    int start = rp[node], deg = cnt[node];
    float acc = X[(size_t)node * N_CLASS + f];
    int j = 0;
    for (; j + 8 <= deg; j += 8) {
        int s0 = col[start + j],     s1 = col[start + j + 1];
        int s2 = col[start + j + 2], s3 = col[start + j + 3];
        int s4 = col[start + j + 4], s5 = col[start + j + 5];
        int s6 = col[start + j + 6], s7 = col[start + j + 7];
        float v0 = X[(size_t)s0 * N_CLASS + f];
        float v1 = X[(size_t)s1 * N_CLASS + f];
        float v2 = X[(size_t)s2 * N_CLASS + f];
        float v3 = X[(size_t)s3 * N_CLASS + f];
        float v4 = X[(size_t)s4 * N_CLASS + f];
        float v5 = X[(size_t)s5 * N_CLASS + f];
        float v6 = X[(size_t)s6 * N_CLASS + f];
        float v7 = X[(size_t)s7 * N_CLASS + f];
        acc += v0; acc += v1; acc += v2; acc += v3;
        acc += v4; acc += v5; acc += v6; acc += v7;
    }
    for (; j < deg; ++j)
        acc += X[(size_t)col[start + j] * N_CLASS + f];
    out[(size_t)node * N_CLASS + f] = acc;
}

// ===== layer-2 gather, bf16 features, fused BN+ReLU, 8x-unrolled loads ======
__global__ __launch_bounds__(256) void gather_bn_k(
    const unsigned short* __restrict__ X, const int* __restrict__ col,
    const int* __restrict__ rp, const int* __restrict__ cnt,
    const float* __restrict__ st, const float* __restrict__ g,
    const float* __restrict__ b, unsigned short* __restrict__ out,
    int N, float inv_n) {
    int wave = (blockIdx.x * 256 + threadIdx.x) >> 6;
    int lane = threadIdx.x & 63;
    if (wave >= N) return;
    int c0 = lane * 2;
    float m0 = st[c0] * inv_n,      m1 = st[c0 + 1] * inv_n;
    float v0_ = fmaxf(st[128 + c0] * inv_n - m0 * m0, 0.f);
    float v1_ = fmaxf(st[128 + c0 + 1] * inv_n - m1 * m1, 0.f);
    float s0 = g[c0] * rsqrtf(v0_ + BN_EPS), s1 = g[c0 + 1] * rsqrtf(v1_ + BN_EPS);
    float h0 = b[c0] - m0 * s0,             h1 = b[c0 + 1] - m1 * s1;
    int start = rp[wave], deg = cnt[wave];
    const unsigned int* Xv = (const unsigned int*)X;   // 2 bf16 per uint
    unsigned int self = Xv[(size_t)wave * 64 + lane];
    float a0 = fmaxf(fmaf(bf2f(self & 0xffffu), s0, h0), 0.f);
    float a1 = fmaxf(fmaf(bf2f(self >> 16),    s1, h1), 0.f);
    int j = 0;
    for (; j + 8 <= deg; j += 8) {
        int n0 = col[start + j],     n1 = col[start + j + 1];
        int n2 = col[start + j + 2], n3 = col[start + j + 3];
        int n4 = col[start + j + 4], n5 = col[start + j + 5];
        int n6 = col[start + j + 6], n7 = col[start + j + 7];
        unsigned int w0 = Xv[(size_t)n0 * 64 + lane];
        unsigned int w1 = Xv[(size_t)n1 * 64 + lane];
        unsigned int w2 = Xv[(size_t)n2 * 64 + lane];
        unsigned int w3 = Xv[(size_t)n3 * 64 + lane];
        unsigned int w4 = Xv[(size_t)n4 * 64 + lane];
        unsigned int w5 = Xv[(size_t)n5 * 64 + lane];
        unsigned int w6 = Xv[(size_t)n6 * 64 + lane];
        unsigned int w7 = Xv[(size_t)n7 * 64 + lane];
        a0 += fmaxf(fmaf(bf2f(w0 & 0xffffu), s0, h0), 0.f);
        a1 += fmaxf(fmaf(bf2f(w0 >> 16),    s1, h1), 0.f);
        a0 += fmaxf(fmaf(bf2f(w1 & 0xffffu), s0, h0), 0.f);
        a1 += fmaxf(fmaf(bf2f(w1 >> 16),    s1, h1), 0.f);
        a0 += fmaxf(fmaf(bf2f(w2 & 0xffffu), s0, h0), 0.f);
        a1 += fmaxf(fmaf(bf2f(w2 >> 16),    s1, h1), 0.f);
        a0 += fmaxf(fmaf(bf2f(w3 & 0xffffu), s0, h0), 0.f);
        a1 += fmaxf(fmaf(bf2f(w3 >> 16),    s1, h1), 0.f);
        a0 += fmaxf(fmaf(bf2f(w4 & 0xffffu), s0, h0), 0.f);
        a1 += fmaxf(fmaf(bf2f(w4 >> 16),    s1, h1), 0.f);
        a0 += fmaxf(fmaf(bf2f(w5 & 0xffffu), s0, h0), 0.f);
        a1 += fmaxf(fmaf(bf2f(w5 >> 16),    s1, h1), 0.f);
        a0 += fmaxf(fmaf(bf2f(w6 & 0xffffu), s0, h0), 0.f);
        a1 += fmaxf(fmaf(bf2f(w6 >> 16),    s1, h1), 0.f);
        a0 += fmaxf(fmaf(bf2f(w7 & 0xffffu), s0, h0), 0.f);
        a1 += fmaxf(fmaf(bf2f(w7 >> 16),    s1, h1), 0.f);
    }
    for (; j < deg; ++j) {
        int s = col[start + j];
        unsigned int v = Xv[(size_t)s * 64 + lane];
        a0 += fmaxf(fmaf(bf2f(v & 0xffffu), s0, h0), 0.f);
        a1 += fmaxf(fmaf(bf2f(v >> 16),    s1, h1), 0.f);
    }
    unsigned int o = (unsigned int)f2bf(a0) | ((unsigned int)f2bf(a1) << 16);
    ((unsigned int*)out)[(size_t)wave * 64 + lane] = o;
}

// ======== K=10 GEMM + bias + fp32 column-stats, bf16 output =================
__global__ __launch_bounds__(128) void gemm10_k(
    const float* __restrict__ A, const float* __restrict__ W,
    const float* __restrict__ bias, unsigned short* __restrict__ C,
    float* __restrict__ stOut, int N) {
    __shared__ float rb[16 * N_CLASS];
    const int tid = threadIdx.x;
    float wreg[N_CLASS];
#pragma unroll
    for (int k = 0; k < N_CLASS; ++k) wreg[k] = W[k * HIDDEN + tid];
    float bb = bias[tid];
    float s = 0.f, s2 = 0.f;
    for (int r0 = blockIdx.x * 16; r0 < N; r0 += gridDim.x * 16) {
        int nr = min(16, N - r0);
        for (int i = tid; i < nr * N_CLASS; i += 128) rb[i] = A[r0 * N_CLASS + i];
        __syncthreads();
        for (int r = 0; r < nr; ++r) {
            float acc = bb;
#pragma unroll
            for (int k = 0; k < N_CLASS; ++k) acc = fmaf(rb[r * N_CLASS + k], wreg[k], acc);
            C[(size_t)(r0 + r) * HIDDEN + tid] = f2bf(acc);
            s += acc; s2 += acc * acc;
        }
        __syncthreads();
    }
    atomicAdd(stOut + tid, s);
    atomicAdd(stOut + HIDDEN + tid, s2);
}

// ============ MFMA bf16 GEMM: Zout = [bnrelu](Zin) @ W + bias ===============
// 256 threads = 4 waves; 64-row x 128-col tile per iteration; K=128.
// Wt[n][k] bf16 pre-transposed. 16x16x32 MFMA, verified layouts (m89/m91):
//   A: m=lane&15, k=(lane>>4)*8+j   B: n=lane&15, k=(lane>>4)*8+j
//   C: col=lane&15, row=(lane>>4)*4+reg
// LDS row stride 136 bf16 (272 B) -> b128 reads are <=2-way conflicts (free).
template<bool BN>
__global__ __launch_bounds__(256) void gemm_mfma_k(
    const unsigned short* __restrict__ Zin, const unsigned short* __restrict__ Wt,
    const float* __restrict__ bias,
    const float* __restrict__ stIn, const float* __restrict__ gIn,
    const float* __restrict__ tIn,
    unsigned short* __restrict__ Zout, float* __restrict__ stOut,
    int N, float inv_n) {
    __shared__ unsigned short Wl[128 * 136];    // 34.8 KB
    __shared__ unsigned short Al[64 * 136];     // 17.4 KB (reused for C out)
    __shared__ float sTab[128], hTab[128], biasTab[128];
    __shared__ float redS[128], redS2[128];

    const int tid  = threadIdx.x;
    const int wv   = tid >> 6;
    const int ln   = tid & 63;
    const int half = ln >> 4;
    const int l16  = ln & 15;

    if (tid < 128) {
        biasTab[tid] = bias[tid];
        if (BN) {
            float m = stIn[tid] * inv_n;
            float v = fmaxf(stIn[128 + tid] * inv_n - m * m, 0.f);
            float s = gIn[tid] * rsqrtf(v + BN_EPS);
            sTab[tid] = s;
            hTab[tid] = tIn[tid] - m * s;
        }
        redS[tid] = 0.f; redS2[tid] = 0.f;
    }
    // stage Wt into LDS (row stride 136)
    for (int c = tid; c < 2048; c += 256) {
        int n = c >> 4, k8 = c & 15;
        uint4 v = *(const uint4*)(Wt + (size_t)n * 128 + k8 * 8);
        *(uint4*)(&Wl[n * 136 + k8 * 8]) = v;
    }
    __syncthreads();

    float cs[8], cs2[8];
#pragma unroll
    for (int i = 0; i < 8; ++i) { cs[i] = 0.f; cs2[i] = 0.f; }

    const int ntiles = (N + 63) >> 6;
    for (int tile = blockIdx.x; tile < ntiles; tile += gridDim.x) {
        const int r0 = tile * 64;
        // ---- stage A (64 x 128 bf16), optional BN+ReLU ----
        for (int c = tid; c < 1024; c += 256) {
            int r = c >> 4, k8 = c & 15;
            int gr = r0 + r; if (gr >= N) gr = N - 1;   // clamp; garbage rows unused
            uint4 v = *(const uint4*)(Zin + (size_t)gr * 128 + k8 * 8);
            if (BN) {
                unsigned short* us = (unsigned short*)&v;
                int kb = k8 * 8;
#pragma unroll
                for (int j = 0; j < 8; ++j) {
                    float f = fmaxf(fmaf(bf2f(us[j]), sTab[kb + j], hTab[kb + j]), 0.f);
                    us[j] = f2bf(f);
                }
            }
            *(uint4*)(&Al[r * 136 + k8 * 8]) = v;
        }
        __syncthreads();

        // ---- preload A fragments (wave wv owns rows wv*16..+15) ----
        short8 afrag[4];
        const int arow = wv * 16 + l16;
#pragma unroll
        for (int s = 0; s < 4; ++s)
            afrag[s] = *(const short8*)(&Al[arow * 136 + s * 32 + half * 8]);
        __syncthreads();   // Al now reusable as C buffer

        // ---- 8 col-tiles x 4 K-steps ----
#pragma unroll
        for (int ct = 0; ct < 8; ++ct) {
            floatx4 acc = {0.f, 0.f, 0.f, 0.f};
            const int bn_ = ct * 16 + l16;
#pragma unroll
            for (int s = 0; s < 4; ++s) {
                short8 bfrag = *(const short8*)(&Wl[bn_ * 136 + s * 32 + half * 8]);
                acc = __builtin_amdgcn_mfma_f32_16x16x32_bf16(afrag[s], bfrag, acc, 0, 0, 0);
            }
            float bcol = biasTab[bn_];
#pragma unroll
            for (int r = 0; r < 4; ++r) {
                int lrow = wv * 16 + half * 4 + r;
                float val = acc[r] + bcol;
                if (r0 + lrow < N) { cs[ct] += val; cs2[ct] += val * val; }
                Al[lrow * 136 + bn_] = f2bf(val);
            }
        }
        __syncthreads();

        // ---- coalesced C writeback ----
        for (int c = tid; c < 1024; c += 256) {
            int r = c >> 4, k8 = c & 15;
            int gr = r0 + r;
            if (gr < N)
                *(uint4*)(Zout + (size_t)gr * 128 + k8 * 8) = *(const uint4*)(&Al[r * 136 + k8 * 8]);
        }
        __syncthreads();
    }

    // ---- stats reduction: quads of a wave hold same col -> shuffle, LDS, global
#pragma unroll
    for (int ct = 0; ct < 8; ++ct) {
        float a = cs[ct], b = cs2[ct];
        a += __shfl_xor(a, 16); a += __shfl_xor(a, 32);
        b += __shfl_xor(b, 16); b += __shfl_xor(b, 32);
        if (half == 0) {
            atomicAdd(&redS[ct * 16 + l16], a);
            atomicAdd(&redS2[ct * 16 + l16], b);
        }
    }
    __syncthreads();
    if (tid < 128) {
        atomicAdd(stOut + tid, redS[tid]);
        atomicAdd(stOut + 128 + tid, redS2[tid]);
    }
}

// ====== final: BN+ReLU -> @wf + bf -> log_softmax, one wave per node ========
__global__ void final_lsm_k(const unsigned short* __restrict__ H, const float* __restrict__ st,
                            const float* __restrict__ g, const float* __restrict__ b,
                            const float* __restrict__ wf, const float* __restrict__ bf,
                            float* __restrict__ out, int N, float inv_n) {
    int gid = blockIdx.x * blockDim.x + threadIdx.x;
    int node = gid >> 6;
    int lane = gid & 63;
    if (node >= N) return;
    int c0 = lane, c1 = lane + 64;
    float m0 = st[c0] * inv_n, m1 = st[c1] * inv_n;
    float v0 = fmaxf(st[128 + c0] * inv_n - m0 * m0, 0.f);
    float v1 = fmaxf(st[128 + c1] * inv_n - m1 * m1, 0.f);
    float s0 = g[c0] * rsqrtf(v0 + BN_EPS), s1 = g[c1] * rsqrtf(v1 + BN_EPS);
    float h0 = b[c0] - m0 * s0,            h1 = b[c1] - m1 * s1;
    const unsigned short* h = H + (size_t)node * HIDDEN;
    float a0 = fmaxf(fmaf(bf2f(h[c0]), s0, h0), 0.f);
    float a1 = fmaxf(fmaf(bf2f(h[c1]), s1, h1), 0.f);
    float logit[N_CLASS];
#pragma unroll
    for (int c = 0; c < N_CLASS; ++c) {
        float p = fmaf(a0, wf[c0 * N_CLASS + c], a1 * wf[c1 * N_CLASS + c]);
#pragma unroll
        for (int off = 32; off; off >>= 1) p += __shfl_down(p, off);
        logit[c] = p + bf[c];
    }
    if (lane == 0) {
        float m = logit[0];
#pragma unroll
        for (int c = 1; c < N_CLASS; ++c) m = fmaxf(m, logit[c]);
        float s = 0.f;
#pragma unroll
        for (int c = 0; c < N_CLASS; ++c) s += expf(logit[c] - m);
        float lse = logf(s);
#pragma unroll
        for (int c = 0; c < N_CLASS; ++c)
            out[(size_t)node * N_CLASS + c] = logit[c] - m - lse;
    }
}

// ===========================================================================

extern "C" void kernel_launch(void* const* d_in, const int* in_sizes, int n_in,
                              void* d_out, int out_size, void* d_ws, size_t ws_size,
                              hipStream_t stream) {
    const float* x   = (const float*)d_in[0];
    const float* w11 = (const float*)d_in[2];
    const float* b11 = (const float*)d_in[3];
    const float* g11 = (const float*)d_in[4];
    const float* t11 = (const float*)d_in[5];
    const float* w12 = (const float*)d_in[6];
    const float* b12 = (const float*)d_in[7];
    const float* g12 = (const float*)d_in[8];
    const float* t12 = (const float*)d_in[9];
    const float* w21 = (const float*)d_in[10];
    const float* b21 = (const float*)d_in[11];
    const float* g21 = (const float*)d_in[12];
    const float* t21 = (const float*)d_in[13];
    const float* w22 = (const float*)d_in[14];
    const float* b22 = (const float*)d_in[15];
    const float* g22 = (const float*)d_in[16];
    const float* t22 = (const float*)d_in[17];
    const float* wf  = (const float*)d_in[18];
    const float* bf  = (const float*)d_in[19];
    const int*   ei  = (const int*)d_in[20];

    const int N = in_sizes[0] / N_CLASS;      // 100000
    const int E = in_sizes[1];                // 1600000
    const float inv_n = 1.0f / (float)N;

    // ---- workspace layout (16B-aligned sections) ----
    char* base = (char*)d_ws;
    size_t off = 0;
    auto take = [&](size_t bytes) { void* p = base + off; off += (bytes + 15) & ~(size_t)15; return p; };
    float*          stats   = (float*)take(1024 * 4);
    float*          h0      = (float*)take((size_t)N * N_CLASS * 4);
    int*            cnt     = (int*)take((size_t)N * 4);
    int*            row_ptr = (int*)take((size_t)N * 4);
    int*            rank    = (int*)take((size_t)E * 4);
    int*            bsum    = (int*)take(512 * 4);
    int*            col     = (int*)take((size_t)E * 4);
    unsigned short* bufA    = (unsigned short*)take((size_t)N * HIDDEN * 2);
    unsigned short* bufB    = (unsigned short*)take((size_t)N * HIDDEN * 2);
    unsigned short* Wt1     = (unsigned short*)take(128 * 128 * 2);
    unsigned short* Wt2     = (unsigned short*)take(128 * 128 * 2);
    unsigned short* Wt3     = (unsigned short*)take(128 * 128 * 2);

    const int nB = (N + 255) / 256;
    const int gE = (E + 255) / 256;

    (void)hipMemsetAsync(stats, 0, 1024 * sizeof(float), stream);
    (void)hipMemsetAsync(cnt, 0, (size_t)N * sizeof(int), stream);

    // ---- weight prep (bf16, transposed) ----
    prepw_k<<<64, 256, 0, stream>>>(w12, Wt1);
    prepw_k<<<64, 256, 0, stream>>>(w21, Wt2);
    prepw_k<<<64, 256, 0, stream>>>(w22, Wt3);

    // ---- CSR build (by dst), atomic-free locality-passed fill ----
    hist_k<<<gE, 256, 0, stream>>>(ei, cnt, rank, E);
    scanA_k<<<nB, 256, 0, stream>>>(cnt, bsum, N);
    scanB_k<<<1, 512, 0, stream>>>(bsum, nB);
    scanC_k<<<nB, 256, 0, stream>>>(cnt, bsum, row_ptr, N);
    fill_k<<<gE, 256, 0, stream>>>(ei, rank, row_ptr, col, E, N);

    // ---- layer 1 ----
    gather10_k<<<(N * N_CLASS + 255) / 256, 256, 0, stream>>>(x, col, row_ptr, cnt, h0, N);
    gemm10_k<<<512, 128, 0, stream>>>(h0, w11, b11, bufA, stats, N);            // Z1 + stats0
    gemm_mfma_k<true><<<512, 256, 0, stream>>>(bufA, Wt1, b12, stats, g11, t11,
                                               bufB, stats + 256, N, inv_n);    // Z2 + stats1

    // ---- layer 2 aggregation (BN2+ReLU fused) ----
    gather_bn_k<<<(N * 64 + 255) / 256, 256, 0, stream>>>(bufB, col, row_ptr, cnt,
                                                          stats + 256, g12, t12, bufA, N, inv_n);

    // ---- layer 2 MLP ----
    gemm_mfma_k<false><<<512, 256, 0, stream>>>(bufA, Wt2, b21, nullptr, nullptr, nullptr,
                                                bufB, stats + 512, N, inv_n);   // Z3 + stats2
    gemm_mfma_k<true><<<512, 256, 0, stream>>>(bufB, Wt3, b22, stats + 512, g21, t21,
                                               bufA, stats + 768, N, inv_n);    // Z4 + stats3

    // ---- final linear + log_softmax (BN4+ReLU fused) ----
    final_lsm_k<<<(N * 64 + 255) / 256, 256, 0, stream>>>(bufA, stats + 768, g22, t22,
                                                          wf, bf, (float*)d_out, N, inv_n);
}

// Round 7
// 439.761 us; speedup vs baseline: 4.2375x; 1.1147x over previous
//
#include <hip/hip_runtime.h>

#define N_CLASS 10
#define HIDDEN 128
#define BN_EPS 1e-5f

typedef short short8 __attribute__((ext_vector_type(8)));   // 8 bf16 in 4 VGPRs
typedef float floatx4 __attribute__((ext_vector_type(4)));

__device__ __forceinline__ float bf2f(unsigned short u) {
    unsigned int x = ((unsigned int)u) << 16;
    float f; __builtin_memcpy(&f, &x, 4); return f;
}
__device__ __forceinline__ unsigned short f2bf(float f) {
    unsigned int x; __builtin_memcpy(&x, &f, 4);
    x += 0x7FFFu + ((x >> 16) & 1u);          // round-to-nearest-even
    return (unsigned short)(x >> 16);
}
// exact bf16 unpack of a packed uint, 1 VALU op each
__device__ __forceinline__ float lo_f(unsigned int u) {
    unsigned int x = u << 16; float f; __builtin_memcpy(&f, &x, 4); return f;
}
__device__ __forceinline__ float hi_f(unsigned int u) {
    unsigned int x = u & 0xffff0000u; float f; __builtin_memcpy(&f, &x, 4); return f;
}

// ============================ CSR build =====================================
// hist: per-dst degree count AND per-edge rank (slot within its dst row)
__global__ void hist_k(const int* __restrict__ ei, int* __restrict__ cnt,
                       int* __restrict__ rank, int E) {
    int e = blockIdx.x * 256 + threadIdx.x;
    if (e < E) rank[e] = atomicAdd(cnt + ei[E + e], 1);
}

__global__ void scanA_k(const int* __restrict__ cnt, int* __restrict__ bsum, int N) {
    __shared__ int sm[256];
    int i = blockIdx.x * 256 + threadIdx.x;
    sm[threadIdx.x] = (i < N) ? cnt[i] : 0;
    __syncthreads();
    for (int s = 128; s > 0; s >>= 1) {
        if (threadIdx.x < s) sm[threadIdx.x] += sm[threadIdx.x + s];
        __syncthreads();
    }
    if (threadIdx.x == 0) bsum[blockIdx.x] = sm[0];
}

__global__ void scanB_k(int* __restrict__ bsum, int B) {
    __shared__ int sm[512];
    int t = threadIdx.x;
    sm[t] = (t < B) ? bsum[t] : 0;
    __syncthreads();
    for (int off = 1; off < 512; off <<= 1) {
        int u = (t >= off) ? sm[t - off] : 0;
        __syncthreads();
        sm[t] += u;
        __syncthreads();
    }
    if (t < B) bsum[t] = (t == 0) ? 0 : sm[t - 1];
}

__global__ void scanC_k(const int* __restrict__ cnt, const int* __restrict__ boff,
                        int* __restrict__ row_ptr, int N) {
    __shared__ int sm[256];
    int i = blockIdx.x * 256 + threadIdx.x;
    int t = threadIdx.x;
    int v = (i < N) ? cnt[i] : 0;
    sm[t] = v;
    __syncthreads();
    for (int off = 1; off < 256; off <<= 1) {
        int u = (t >= off) ? sm[t - off] : 0;
        __syncthreads();
        sm[t] += u;
        __syncthreads();
    }
    if (i < N) row_ptr[i] = boff[blockIdx.x] + sm[t] - v;
}

// Atomic-free fill in P dst-range passes (writes stay in a per-XCD-L2-sized window)
__global__ void fill_k(const int* __restrict__ ei, const int* __restrict__ rank,
                       const int* __restrict__ rp, int* __restrict__ col,
                       int E, int N) {
    const int P = 4;
    const int rs = (N + P - 1) / P;
    const int stride = gridDim.x * 256;
#pragma unroll 1
    for (int pass = 0; pass < P; ++pass) {
        int lo = pass * rs, hi = lo + rs;
        for (int e = blockIdx.x * 256 + threadIdx.x; e < E; e += stride) {
            int d = ei[E + e];
            if (d >= lo && d < hi)
                col[rp[d] + rank[e]] = ei[e];
        }
    }
}

// ============== W[k][n] fp32 -> Wt[n][k] bf16, 3 weights in one launch ======
__global__ void prepw_k(const float* __restrict__ W0, const float* __restrict__ W1,
                        const float* __restrict__ W2,
                        unsigned short* __restrict__ T0, unsigned short* __restrict__ T1,
                        unsigned short* __restrict__ T2) {
    const float* W = (blockIdx.y == 0) ? W0 : (blockIdx.y == 1) ? W1 : W2;
    unsigned short* T = (blockIdx.y == 0) ? T0 : (blockIdx.y == 1) ? T1 : T2;
    int i = blockIdx.x * 256 + threadIdx.x;
    if (i < 128 * 128) {
        int k = i >> 7, n = i & 127;
        T[n * 128 + k] = f2bf(W[k * 128 + n]);
    }
}

// ===================== layer-1 gather: h0 = x + sum x[src] ==================
__global__ void gather10_k(const float* __restrict__ X, const int* __restrict__ col,
                           const int* __restrict__ rp, const int* __restrict__ cnt,
                           float* __restrict__ out, int N) {
    int t = blockIdx.x * 256 + threadIdx.x;
    int node = t / N_CLASS, f = t - node * N_CLASS;
    if (node >= N) return;
    int start = rp[node], deg = cnt[node];
    float acc = X[(size_t)node * N_CLASS + f];
    int j = 0;
    for (; j + 8 <= deg; j += 8) {
        int s0 = col[start + j],     s1 = col[start + j + 1];
        int s2 = col[start + j + 2], s3 = col[start + j + 3];
        int s4 = col[start + j + 4], s5 = col[start + j + 5];
        int s6 = col[start + j + 6], s7 = col[start + j + 7];
        float v0 = X[(size_t)s0 * N_CLASS + f];
        float v1 = X[(size_t)s1 * N_CLASS + f];
        float v2 = X[(size_t)s2 * N_CLASS + f];
        float v3 = X[(size_t)s3 * N_CLASS + f];
        float v4 = X[(size_t)s4 * N_CLASS + f];
        float v5 = X[(size_t)s5 * N_CLASS + f];
        float v6 = X[(size_t)s6 * N_CLASS + f];
        float v7 = X[(size_t)s7 * N_CLASS + f];
        acc += v0; acc += v1; acc += v2; acc += v3;
        acc += v4; acc += v5; acc += v6; acc += v7;
    }
    for (; j < deg; ++j)
        acc += X[(size_t)col[start + j] * N_CLASS + f];
    out[(size_t)node * N_CLASS + f] = acc;
}

// ======= pre-activation: R = bnrelu(Z), once per node (N x 128 bf16) ========
__global__ __launch_bounds__(256) void act2_k(
    const unsigned short* __restrict__ Z, unsigned short* __restrict__ R,
    const float* __restrict__ st, const float* __restrict__ g,
    const float* __restrict__ b, int N, float inv_n) {
    __shared__ float sTab[128], hTab[128];
    int tid = threadIdx.x;
    if (tid < 128) {
        float m = st[tid] * inv_n;
        float v = fmaxf(st[128 + tid] * inv_n - m * m, 0.f);
        float s = g[tid] * rsqrtf(v + BN_EPS);
        sTab[tid] = s;
        hTab[tid] = b[tid] - m * s;
    }
    __syncthreads();
    int total = N * 16;                       // uint4 count
    for (int i = blockIdx.x * 256 + tid; i < total; i += gridDim.x * 256) {
        int k8 = (i & 15) * 8;
        uint4 v = ((const uint4*)Z)[i];
        unsigned short* us = (unsigned short*)&v;
#pragma unroll
        for (int j = 0; j < 8; ++j) {
            float f = fmaxf(fmaf(bf2f(us[j]), sTab[k8 + j], hTab[k8 + j]), 0.f);
            us[j] = f2bf(f);
        }
        ((uint4*)R)[i] = v;
    }
}

// ========== layer-2 gather: pure bf16 sum of activated rows =================
__global__ __launch_bounds__(256) void gather_sum_k(
    const unsigned short* __restrict__ R, const int* __restrict__ col,
    const int* __restrict__ rp, const int* __restrict__ cnt,
    unsigned short* __restrict__ out, int N) {
    int wave = (blockIdx.x * 256 + threadIdx.x) >> 6;
    int lane = threadIdx.x & 63;
    if (wave >= N) return;
    int start = rp[wave], deg = cnt[wave];
    const unsigned int* Xv = (const unsigned int*)R;   // 2 bf16 per uint
    unsigned int self = Xv[(size_t)wave * 64 + lane];
    float a0 = lo_f(self);
    float a1 = hi_f(self);
    int j = 0;
    for (; j + 8 <= deg; j += 8) {
        int n0 = col[start + j],     n1 = col[start + j + 1];
        int n2 = col[start + j + 2], n3 = col[start + j + 3];
        int n4 = col[start + j + 4], n5 = col[start + j + 5];
        int n6 = col[start + j + 6], n7 = col[start + j + 7];
        unsigned int w0 = Xv[(size_t)n0 * 64 + lane];
        unsigned int w1 = Xv[(size_t)n1 * 64 + lane];
        unsigned int w2 = Xv[(size_t)n2 * 64 + lane];
        unsigned int w3 = Xv[(size_t)n3 * 64 + lane];
        unsigned int w4 = Xv[(size_t)n4 * 64 + lane];
        unsigned int w5 = Xv[(size_t)n5 * 64 + lane];
        unsigned int w6 = Xv[(size_t)n6 * 64 + lane];
        unsigned int w7 = Xv[(size_t)n7 * 64 + lane];
        a0 += lo_f(w0); a1 += hi_f(w0);
        a0 += lo_f(w1); a1 += hi_f(w1);
        a0 += lo_f(w2); a1 += hi_f(w2);
        a0 += lo_f(w3); a1 += hi_f(w3);
        a0 += lo_f(w4); a1 += hi_f(w4);
        a0 += lo_f(w5); a1 += hi_f(w5);
        a0 += lo_f(w6); a1 += hi_f(w6);
        a0 += lo_f(w7); a1 += hi_f(w7);
    }
    for (; j < deg; ++j) {
        unsigned int v = Xv[(size_t)col[start + j] * 64 + lane];
        a0 += lo_f(v); a1 += hi_f(v);
    }
    unsigned int o = (unsigned int)f2bf(a0) | ((unsigned int)f2bf(a1) << 16);
    ((unsigned int*)out)[(size_t)wave * 64 + lane] = o;
}

// ======== K=10 GEMM + bias + fp32 column-stats, bf16 output =================
__global__ __launch_bounds__(128) void gemm10_k(
    const float* __restrict__ A, const float* __restrict__ W,
    const float* __restrict__ bias, unsigned short* __restrict__ C,
    float* __restrict__ stOut, int N) {
    __shared__ float rb[16 * N_CLASS];
    const int tid = threadIdx.x;
    float wreg[N_CLASS];
#pragma unroll
    for (int k = 0; k < N_CLASS; ++k) wreg[k] = W[k * HIDDEN + tid];
    float bb = bias[tid];
    float s = 0.f, s2 = 0.f;
    for (int r0 = blockIdx.x * 16; r0 < N; r0 += gridDim.x * 16) {
        int nr = min(16, N - r0);
        for (int i = tid; i < nr * N_CLASS; i += 128) rb[i] = A[r0 * N_CLASS + i];
        __syncthreads();
        for (int r = 0; r < nr; ++r) {
            float acc = bb;
#pragma unroll
            for (int k = 0; k < N_CLASS; ++k) acc = fmaf(rb[r * N_CLASS + k], wreg[k], acc);
            C[(size_t)(r0 + r) * HIDDEN + tid] = f2bf(acc);
            s += acc; s2 += acc * acc;
        }
        __syncthreads();
    }
    atomicAdd(stOut + tid, s);
    atomicAdd(stOut + HIDDEN + tid, s2);
}

// ============ MFMA bf16 GEMM: Zout = [bnrelu](Zin) @ W + bias ===============
template<bool BN>
__global__ __launch_bounds__(256) void gemm_mfma_k(
    const unsigned short* __restrict__ Zin, const unsigned short* __restrict__ Wt,
    const float* __restrict__ bias,
    const float* __restrict__ stIn, const float* __restrict__ gIn,
    const float* __restrict__ tIn,
    unsigned short* __restrict__ Zout, float* __restrict__ stOut,
    int N, float inv_n) {
    __shared__ unsigned short Wl[128 * 136];    // 34.8 KB
    __shared__ unsigned short Al[64 * 136];     // 17.4 KB (reused for C out)
    __shared__ float sTab[128], hTab[128], biasTab[128];
    __shared__ float redS[128], redS2[128];

    const int tid  = threadIdx.x;
    const int wv   = tid >> 6;
    const int ln   = tid & 63;
    const int half = ln >> 4;
    const int l16  = ln & 15;

    if (tid < 128) {
        biasTab[tid] = bias[tid];
        if (BN) {
            float m = stIn[tid] * inv_n;
            float v = fmaxf(stIn[128 + tid] * inv_n - m * m, 0.f);
            float s = gIn[tid] * rsqrtf(v + BN_EPS);
            sTab[tid] = s;
            hTab[tid] = tIn[tid] - m * s;
        }
        redS[tid] = 0.f; redS2[tid] = 0.f;
    }
    for (int c = tid; c < 2048; c += 256) {
        int n = c >> 4, k8 = c & 15;
        uint4 v = *(const uint4*)(Wt + (size_t)n * 128 + k8 * 8);
        *(uint4*)(&Wl[n * 136 + k8 * 8]) = v;
    }
    __syncthreads();

    float cs[8], cs2[8];
#pragma unroll
    for (int i = 0; i < 8; ++i) { cs[i] = 0.f; cs2[i] = 0.f; }

    const int ntiles = (N + 63) >> 6;
    for (int tile = blockIdx.x; tile < ntiles; tile += gridDim.x) {
        const int r0 = tile * 64;
        for (int c = tid; c < 1024; c += 256) {
            int r = c >> 4, k8 = c & 15;
            int gr = r0 + r; if (gr >= N) gr = N - 1;
            uint4 v = *(const uint4*)(Zin + (size_t)gr * 128 + k8 * 8);
            if (BN) {
                unsigned short* us = (unsigned short*)&v;
                int kb = k8 * 8;
#pragma unroll
                for (int j = 0; j < 8; ++j) {
                    float f = fmaxf(fmaf(bf2f(us[j]), sTab[kb + j], hTab[kb + j]), 0.f);
                    us[j] = f2bf(f);
                }
            }
            *(uint4*)(&Al[r * 136 + k8 * 8]) = v;
        }
        __syncthreads();

        short8 afrag[4];
        const int arow = wv * 16 + l16;
#pragma unroll
        for (int s = 0; s < 4; ++s)
            afrag[s] = *(const short8*)(&Al[arow * 136 + s * 32 + half * 8]);
        __syncthreads();

#pragma unroll
        for (int ct = 0; ct < 8; ++ct) {
            floatx4 acc = {0.f, 0.f, 0.f, 0.f};
            const int bn_ = ct * 16 + l16;
#pragma unroll
            for (int s = 0; s < 4; ++s) {
                short8 bfrag = *(const short8*)(&Wl[bn_ * 136 + s * 32 + half * 8]);
                acc = __builtin_amdgcn_mfma_f32_16x16x32_bf16(afrag[s], bfrag, acc, 0, 0, 0);
            }
            float bcol = biasTab[bn_];
#pragma unroll
            for (int r = 0; r < 4; ++r) {
                int lrow = wv * 16 + half * 4 + r;
                float val = acc[r] + bcol;
                if (r0 + lrow < N) { cs[ct] += val; cs2[ct] += val * val; }
                Al[lrow * 136 + bn_] = f2bf(val);
            }
        }
        __syncthreads();

        for (int c = tid; c < 1024; c += 256) {
            int r = c >> 4, k8 = c & 15;
            int gr = r0 + r;
            if (gr < N)
                *(uint4*)(Zout + (size_t)gr * 128 + k8 * 8) = *(const uint4*)(&Al[r * 136 + k8 * 8]);
        }
        __syncthreads();
    }

#pragma unroll
    for (int ct = 0; ct < 8; ++ct) {
        float a = cs[ct], b = cs2[ct];
        a += __shfl_xor(a, 16); a += __shfl_xor(a, 32);
        b += __shfl_xor(b, 16); b += __shfl_xor(b, 32);
        if (half == 0) {
            atomicAdd(&redS[ct * 16 + l16], a);
            atomicAdd(&redS2[ct * 16 + l16], b);
        }
    }
    __syncthreads();
    if (tid < 128) {
        atomicAdd(stOut + tid, redS[tid]);
        atomicAdd(stOut + 128 + tid, redS2[tid]);
    }
}

// ==== final: BN+ReLU -> @wf + bf -> log_softmax, MFMA (wf padded 10->16) ====
__global__ __launch_bounds__(256) void final_mfma_k(
    const unsigned short* __restrict__ Z, const float* __restrict__ st,
    const float* __restrict__ g, const float* __restrict__ b,
    const float* __restrict__ wf, const float* __restrict__ bfc,
    float* __restrict__ out, int N, float inv_n) {
    __shared__ unsigned short Al[64 * 136];     // 17.4 KB
    __shared__ unsigned short Bl[16 * 136];     // 4.4 KB
    __shared__ float sTab[128], hTab[128], biasTab[16];

    const int tid  = threadIdx.x;
    const int wv   = tid >> 6;
    const int ln   = tid & 63;
    const int half = ln >> 4;
    const int l16  = ln & 15;

    if (tid < 128) {
        float m = st[tid] * inv_n;
        float v = fmaxf(st[128 + tid] * inv_n - m * m, 0.f);
        float s = g[tid] * rsqrtf(v + BN_EPS);
        sTab[tid] = s;
        hTab[tid] = b[tid] - m * s;
    }
    if (tid < 16) biasTab[tid] = (tid < N_CLASS) ? bfc[tid] : -3.0e38f;
    {   // Bl[n][k] = f2bf(wf[k][n]) for n<10, else 0;  16 rows x 128 k
        int n = tid >> 4, k8 = (tid & 15) * 8;
        uint4 v;
        unsigned short* us = (unsigned short*)&v;
#pragma unroll
        for (int j = 0; j < 8; ++j)
            us[j] = (n < N_CLASS) ? f2bf(wf[(k8 + j) * N_CLASS + n]) : (unsigned short)0;
        *(uint4*)(&Bl[n * 136 + k8]) = v;
    }
    __syncthreads();

    short8 bfrag[4];
#pragma unroll
    for (int s = 0; s < 4; ++s)
        bfrag[s] = *(const short8*)(&Bl[l16 * 136 + s * 32 + half * 8]);

    const int ntiles = (N + 63) >> 6;
    for (int tile = blockIdx.x; tile < ntiles; tile += gridDim.x) {
        const int r0 = tile * 64;
        for (int c = tid; c < 1024; c += 256) {
            int r = c >> 4, k8 = c & 15;
            int gr = r0 + r; if (gr >= N) gr = N - 1;
            uint4 v = *(const uint4*)(Z + (size_t)gr * 128 + k8 * 8);
            unsigned short* us = (unsigned short*)&v;
            int kb = k8 * 8;
#pragma unroll
            for (int j = 0; j < 8; ++j) {
                float f = fmaxf(fmaf(bf2f(us[j]), sTab[kb + j], hTab[kb + j]), 0.f);
                us[j] = f2bf(f);
            }
            *(uint4*)(&Al[r * 136 + k8 * 8]) = v;
        }
        __syncthreads();

        short8 afrag[4];
        const int arow = wv * 16 + l16;
#pragma unroll
        for (int s = 0; s < 4; ++s)
            afrag[s] = *(const short8*)(&Al[arow * 136 + s * 32 + half * 8]);
        __syncthreads();    // Al free for next tile's staging

        floatx4 acc = {0.f, 0.f, 0.f, 0.f};
#pragma unroll
        for (int s = 0; s < 4; ++s)
            acc = __builtin_amdgcn_mfma_f32_16x16x32_bf16(afrag[s], bfrag[s], acc, 0, 0, 0);

        // lane l16 holds col l16 of rows wv*16 + half*4 + r; softmax across l16
        float bcol = biasTab[l16];
#pragma unroll
        for (int r = 0; r < 4; ++r) {
            float lg = acc[r] + bcol;                 // -3e38 for pad cols
            float mx = lg;
            mx = fmaxf(mx, __shfl_xor(mx, 1));
            mx = fmaxf(mx, __shfl_xor(mx, 2));
            mx = fmaxf(mx, __shfl_xor(mx, 4));
            mx = fmaxf(mx, __shfl_xor(mx, 8));
            float p = __expf(lg - mx);                // pad cols -> 0
            float se = p;
            se += __shfl_xor(se, 1);
            se += __shfl_xor(se, 2);
            se += __shfl_xor(se, 4);
            se += __shfl_xor(se, 8);
            float ls = __logf(se);
            int grow = r0 + wv * 16 + half * 4 + r;
            if (l16 < N_CLASS && grow < N)
                out[(size_t)grow * N_CLASS + l16] = lg - mx - ls;
        }
    }
}

// ===========================================================================

extern "C" void kernel_launch(void* const* d_in, const int* in_sizes, int n_in,
                              void* d_out, int out_size, void* d_ws, size_t ws_size,
                              hipStream_t stream) {
    const float* x   = (const float*)d_in[0];
    const float* w11 = (const float*)d_in[2];
    const float* b11 = (const float*)d_in[3];
    const float* g11 = (const float*)d_in[4];
    const float* t11 = (const float*)d_in[5];
    const float* w12 = (const float*)d_in[6];
    const float* b12 = (const float*)d_in[7];
    const float* g12 = (const float*)d_in[8];
    const float* t12 = (const float*)d_in[9];
    const float* w21 = (const float*)d_in[10];
    const float* b21 = (const float*)d_in[11];
    const float* g21 = (const float*)d_in[12];
    const float* t21 = (const float*)d_in[13];
    const float* w22 = (const float*)d_in[14];
    const float* b22 = (const float*)d_in[15];
    const float* g22 = (const float*)d_in[16];
    const float* t22 = (const float*)d_in[17];
    const float* wf  = (const float*)d_in[18];
    const float* bf  = (const float*)d_in[19];
    const int*   ei  = (const int*)d_in[20];

    const int N = in_sizes[0] / N_CLASS;      // 100000
    const int E = in_sizes[1];                // 1600000
    const float inv_n = 1.0f / (float)N;

    // ---- workspace layout (16B-aligned sections) ----
    char* base = (char*)d_ws;
    size_t off = 0;
    auto take = [&](size_t bytes) { void* p = base + off; off += (bytes + 15) & ~(size_t)15; return p; };
    float*          stats   = (float*)take(1024 * 4);
    float*          h0      = (float*)take((size_t)N * N_CLASS * 4);
    int*            cnt     = (int*)take((size_t)N * 4);
    int*            row_ptr = (int*)take((size_t)N * 4);
    int*            rank    = (int*)take((size_t)E * 4);
    int*            bsum    = (int*)take(512 * 4);
    int*            col     = (int*)take((size_t)E * 4);
    unsigned short* bufA    = (unsigned short*)take((size_t)N * HIDDEN * 2);
    unsigned short* bufB    = (unsigned short*)take((size_t)N * HIDDEN * 2);
    unsigned short* bufC    = (unsigned short*)take((size_t)N * HIDDEN * 2);
    unsigned short* Wt1     = (unsigned short*)take(128 * 128 * 2);
    unsigned short* Wt2     = (unsigned short*)take(128 * 128 * 2);
    unsigned short* Wt3     = (unsigned short*)take(128 * 128 * 2);

    const int nB = (N + 255) / 256;
    const int gE = (E + 255) / 256;

    (void)hipMemsetAsync(stats, 0, 1024 * sizeof(float), stream);
    (void)hipMemsetAsync(cnt, 0, (size_t)N * sizeof(int), stream);

    // ---- weight prep (bf16, transposed), one dispatch ----
    prepw_k<<<dim3(64, 3), 256, 0, stream>>>(w12, w21, w22, Wt1, Wt2, Wt3);

    // ---- CSR build (by dst), atomic-free locality-passed fill ----
    hist_k<<<gE, 256, 0, stream>>>(ei, cnt, rank, E);
    scanA_k<<<nB, 256, 0, stream>>>(cnt, bsum, N);
    scanB_k<<<1, 512, 0, stream>>>(bsum, nB);
    scanC_k<<<nB, 256, 0, stream>>>(cnt, bsum, row_ptr, N);
    fill_k<<<gE, 256, 0, stream>>>(ei, rank, row_ptr, col, E, N);

    // ---- layer 1 ----
    gather10_k<<<(N * N_CLASS + 255) / 256, 256, 0, stream>>>(x, col, row_ptr, cnt, h0, N);
    gemm10_k<<<512, 128, 0, stream>>>(h0, w11, b11, bufA, stats, N);            // Z1 + stats0
    gemm_mfma_k<true><<<512, 256, 0, stream>>>(bufA, Wt1, b12, stats, g11, t11,
                                               bufB, stats + 256, N, inv_n);    // Z2 + stats1

    // ---- layer 2 aggregation: activate once per node, then pure-sum gather --
    act2_k<<<3125, 256, 0, stream>>>(bufB, bufC, stats + 256, g12, t12, N, inv_n);
    gather_sum_k<<<(N * 64 + 255) / 256, 256, 0, stream>>>(bufC, col, row_ptr, cnt,
                                                           bufA, N);

    // ---- layer 2 MLP ----
    gemm_mfma_k<false><<<512, 256, 0, stream>>>(bufA, Wt2, b21, nullptr, nullptr, nullptr,
                                                bufB, stats + 512, N, inv_n);   // Z3 + stats2
    gemm_mfma_k<true><<<512, 256, 0, stream>>>(bufB, Wt3, b22, stats + 512, g21, t21,
                                               bufA, stats + 768, N, inv_n);    // Z4 + stats3

    // ---- final linear + log_softmax (BN4+ReLU fused, MFMA) ----
    final_mfma_k<<<782, 256, 0, stream>>>(bufA, stats + 768, g22, t22,
                                          wf, bf, (float*)d_out, N, inv_n);
}

// Round 8
// 434.940 us; speedup vs baseline: 4.2844x; 1.0111x over previous
//
#include <hip/hip_runtime.h>

#define N_CLASS 10
#define HIDDEN 128
#define BN_EPS 1e-5f

typedef short short8 __attribute__((ext_vector_type(8)));   // 8 bf16 in 4 VGPRs
typedef float floatx4 __attribute__((ext_vector_type(4)));

__device__ __forceinline__ float bf2f(unsigned short u) {
    unsigned int x = ((unsigned int)u) << 16;
    float f; __builtin_memcpy(&f, &x, 4); return f;
}
__device__ __forceinline__ unsigned short f2bf(float f) {
    unsigned int x; __builtin_memcpy(&x, &f, 4);
    x += 0x7FFFu + ((x >> 16) & 1u);          // round-to-nearest-even
    return (unsigned short)(x >> 16);
}
// exact bf16 unpack of a packed uint, 1 VALU op each
__device__ __forceinline__ float lo_f(unsigned int u) {
    unsigned int x = u << 16; float f; __builtin_memcpy(&f, &x, 4); return f;
}
__device__ __forceinline__ float hi_f(unsigned int u) {
    unsigned int x = u & 0xffff0000u; float f; __builtin_memcpy(&f, &x, 4); return f;
}

// ============================ CSR build =====================================
// hist: per-dst degree count AND per-edge rank (slot within its dst row)
__global__ void hist_k(const int* __restrict__ ei, int* __restrict__ cnt,
                       int* __restrict__ rank, int E) {
    int e = blockIdx.x * 256 + threadIdx.x;
    if (e < E) rank[e] = atomicAdd(cnt + ei[E + e], 1);
}

__global__ void scanA_k(const int* __restrict__ cnt, int* __restrict__ bsum, int N) {
    __shared__ int sm[256];
    int i = blockIdx.x * 256 + threadIdx.x;
    sm[threadIdx.x] = (i < N) ? cnt[i] : 0;
    __syncthreads();
    for (int s = 128; s > 0; s >>= 1) {
        if (threadIdx.x < s) sm[threadIdx.x] += sm[threadIdx.x + s];
        __syncthreads();
    }
    if (threadIdx.x == 0) bsum[blockIdx.x] = sm[0];
}

__global__ void scanB_k(int* __restrict__ bsum, int B) {
    __shared__ int sm[512];
    int t = threadIdx.x;
    sm[t] = (t < B) ? bsum[t] : 0;
    __syncthreads();
    for (int off = 1; off < 512; off <<= 1) {
        int u = (t >= off) ? sm[t - off] : 0;
        __syncthreads();
        sm[t] += u;
        __syncthreads();
    }
    if (t < B) bsum[t] = (t == 0) ? 0 : sm[t - 1];
}

__global__ void scanC_k(const int* __restrict__ cnt, const int* __restrict__ boff,
                        int* __restrict__ row_ptr, int N) {
    __shared__ int sm[256];
    int i = blockIdx.x * 256 + threadIdx.x;
    int t = threadIdx.x;
    int v = (i < N) ? cnt[i] : 0;
    sm[t] = v;
    __syncthreads();
    for (int off = 1; off < 256; off <<= 1) {
        int u = (t >= off) ? sm[t - off] : 0;
        __syncthreads();
        sm[t] += u;
        __syncthreads();
    }
    if (i < N) row_ptr[i] = boff[blockIdx.x] + sm[t] - v;
}

// Atomic-free fill in P dst-range passes (writes stay in a per-XCD-L2-sized window)
__global__ void fill_k(const int* __restrict__ ei, const int* __restrict__ rank,
                       const int* __restrict__ rp, int* __restrict__ col,
                       int E, int N) {
    const int P = 4;
    const int rs = (N + P - 1) / P;
    const int stride = gridDim.x * 256;
#pragma unroll 1
    for (int pass = 0; pass < P; ++pass) {
        int lo = pass * rs, hi = lo + rs;
        for (int e = blockIdx.x * 256 + threadIdx.x; e < E; e += stride) {
            int d = ei[E + e];
            if (d >= lo && d < hi)
                col[rp[d] + rank[e]] = ei[e];
        }
    }
}

// === prep: W[k][n] fp32 -> Wt[n][k] bf16 (x3) + zero stats/cnt (no memsets) ==
__global__ void prep_k(const float* __restrict__ W0, const float* __restrict__ W1,
                       const float* __restrict__ W2,
                       unsigned short* __restrict__ T0, unsigned short* __restrict__ T1,
                       unsigned short* __restrict__ T2,
                       float* __restrict__ stats, int* __restrict__ cnt, int N) {
    const float* W = (blockIdx.y == 0) ? W0 : (blockIdx.y == 1) ? W1 : W2;
    unsigned short* T = (blockIdx.y == 0) ? T0 : (blockIdx.y == 1) ? T1 : T2;
    int i = blockIdx.x * 256 + threadIdx.x;
    if (i < 128 * 128) {
        int k = i >> 7, n = i & 127;
        T[n * 128 + k] = f2bf(W[k * 128 + n]);
    }
    if (blockIdx.y == 0) {
        if (i < 1024) stats[i] = 0.f;
        for (int c = i; c < N; c += 64 * 256) cnt[c] = 0;
    }
}

// ============ pad x [N,10] fp32 -> xp [N,16] fp32 (64B line rows) ===========
__global__ void padx_k(const float* __restrict__ X, float* __restrict__ XP, int N) {
    int i = blockIdx.x * 256 + threadIdx.x;
    if (i >= N * 16) return;
    int node = i >> 4, f = i & 15;
    XP[i] = (f < N_CLASS) ? X[node * N_CLASS + f] : 0.f;
}

// ========= layer-1 gather on padded rows: 16 lanes/node, 1 line/row =========
__global__ void gather10_k(const float* __restrict__ XP, const int* __restrict__ col,
                           const int* __restrict__ rp, const int* __restrict__ cnt,
                           float* __restrict__ out, int N) {
    int t = blockIdx.x * 256 + threadIdx.x;
    int node = t >> 4, f = t & 15;
    if (node >= N) return;
    int start = rp[node], deg = cnt[node];
    float acc = XP[node * 16 + f];
    int j = 0;
    for (; j + 8 <= deg; j += 8) {
        int s0 = col[start + j],     s1 = col[start + j + 1];
        int s2 = col[start + j + 2], s3 = col[start + j + 3];
        int s4 = col[start + j + 4], s5 = col[start + j + 5];
        int s6 = col[start + j + 6], s7 = col[start + j + 7];
        float v0 = XP[s0 * 16 + f];
        float v1 = XP[s1 * 16 + f];
        float v2 = XP[s2 * 16 + f];
        float v3 = XP[s3 * 16 + f];
        float v4 = XP[s4 * 16 + f];
        float v5 = XP[s5 * 16 + f];
        float v6 = XP[s6 * 16 + f];
        float v7 = XP[s7 * 16 + f];
        acc += v0; acc += v1; acc += v2; acc += v3;
        acc += v4; acc += v5; acc += v6; acc += v7;
    }
    for (; j < deg; ++j)
        acc += XP[col[start + j] * 16 + f];
    out[node * 16 + f] = acc;
}

// ======= pre-activation: R = bnrelu(Z), once per node (N x 128 bf16) ========
__global__ __launch_bounds__(256) void act2_k(
    const unsigned short* __restrict__ Z, unsigned short* __restrict__ R,
    const float* __restrict__ st, const float* __restrict__ g,
    const float* __restrict__ b, int N, float inv_n) {
    __shared__ float sTab[128], hTab[128];
    int tid = threadIdx.x;
    if (tid < 128) {
        float m = st[tid] * inv_n;
        float v = fmaxf(st[128 + tid] * inv_n - m * m, 0.f);
        float s = g[tid] * rsqrtf(v + BN_EPS);
        sTab[tid] = s;
        hTab[tid] = b[tid] - m * s;
    }
    __syncthreads();
    int total = N * 16;                       // uint4 count
    for (int i = blockIdx.x * 256 + tid; i < total; i += gridDim.x * 256) {
        int k8 = (i & 15) * 8;
        uint4 v = ((const uint4*)Z)[i];
        unsigned short* us = (unsigned short*)&v;
#pragma unroll
        for (int j = 0; j < 8; ++j) {
            float f = fmaxf(fmaf(bf2f(us[j]), sTab[k8 + j], hTab[k8 + j]), 0.f);
            us[j] = f2bf(f);
        }
        ((uint4*)R)[i] = v;
    }
}

// == layer-2 gather: pure bf16 sum; wave-scalarized CSR reads, 32-bit index ==
__global__ __launch_bounds__(256) void gather_sum_k(
    const unsigned short* __restrict__ R, const int* __restrict__ col,
    const int* __restrict__ rp, const int* __restrict__ cnt,
    unsigned short* __restrict__ out, int N) {
    int wave = __builtin_amdgcn_readfirstlane((blockIdx.x * 256 + threadIdx.x) >> 6);
    int lane = threadIdx.x & 63;
    if (wave >= N) return;
    int start = __builtin_amdgcn_readfirstlane(rp[wave]);
    int deg   = __builtin_amdgcn_readfirstlane(cnt[wave]);
    const unsigned int* Xv = (const unsigned int*)R;   // 2 bf16 per uint
    unsigned int self = Xv[wave * 64 + lane];
    float a0 = lo_f(self);
    float a1 = hi_f(self);
    int j = 0;
    for (; j + 8 <= deg; j += 8) {
        int n0 = col[start + j],     n1 = col[start + j + 1];
        int n2 = col[start + j + 2], n3 = col[start + j + 3];
        int n4 = col[start + j + 4], n5 = col[start + j + 5];
        int n6 = col[start + j + 6], n7 = col[start + j + 7];
        unsigned int w0 = Xv[n0 * 64 + lane];
        unsigned int w1 = Xv[n1 * 64 + lane];
        unsigned int w2 = Xv[n2 * 64 + lane];
        unsigned int w3 = Xv[n3 * 64 + lane];
        unsigned int w4 = Xv[n4 * 64 + lane];
        unsigned int w5 = Xv[n5 * 64 + lane];
        unsigned int w6 = Xv[n6 * 64 + lane];
        unsigned int w7 = Xv[n7 * 64 + lane];
        a0 += lo_f(w0); a1 += hi_f(w0);
        a0 += lo_f(w1); a1 += hi_f(w1);
        a0 += lo_f(w2); a1 += hi_f(w2);
        a0 += lo_f(w3); a1 += hi_f(w3);
        a0 += lo_f(w4); a1 += hi_f(w4);
        a0 += lo_f(w5); a1 += hi_f(w5);
        a0 += lo_f(w6); a1 += hi_f(w6);
        a0 += lo_f(w7); a1 += hi_f(w7);
    }
    for (; j < deg; ++j) {
        unsigned int v = Xv[col[start + j] * 64 + lane];
        a0 += lo_f(v); a1 += hi_f(v);
    }
    unsigned int o = (unsigned int)f2bf(a0) | ((unsigned int)f2bf(a1) << 16);
    ((unsigned int*)out)[wave * 64 + lane] = o;
}

// == K=10 GEMM (padded [N,16] input) + bias + fp32 col-stats, bf16 output ====
__global__ __launch_bounds__(128) void gemm10_k(
    const float* __restrict__ A, const float* __restrict__ W,
    const float* __restrict__ bias, unsigned short* __restrict__ C,
    float* __restrict__ stOut, int N) {
    __shared__ float rb[16 * 16];
    const int tid = threadIdx.x;
    float wreg[N_CLASS];
#pragma unroll
    for (int k = 0; k < N_CLASS; ++k) wreg[k] = W[k * HIDDEN + tid];
    float bb = bias[tid];
    float s = 0.f, s2 = 0.f;
    for (int r0 = blockIdx.x * 16; r0 < N; r0 += gridDim.x * 16) {
        int nr = min(16, N - r0);
        for (int i = tid; i < nr * 16; i += 128) rb[i] = A[r0 * 16 + i];
        __syncthreads();
        for (int r = 0; r < nr; ++r) {
            float acc = bb;
#pragma unroll
            for (int k = 0; k < N_CLASS; ++k) acc = fmaf(rb[r * 16 + k], wreg[k], acc);
            C[(r0 + r) * HIDDEN + tid] = f2bf(acc);
            s += acc; s2 += acc * acc;
        }
        __syncthreads();
    }
    atomicAdd(stOut + tid, s);
    atomicAdd(stOut + HIDDEN + tid, s2);
}

// ============ MFMA bf16 GEMM: Zout = [bnrelu](Zin) @ W + bias ===============
template<bool BN>
__global__ __launch_bounds__(256) void gemm_mfma_k(
    const unsigned short* __restrict__ Zin, const unsigned short* __restrict__ Wt,
    const float* __restrict__ bias,
    const float* __restrict__ stIn, const float* __restrict__ gIn,
    const float* __restrict__ tIn,
    unsigned short* __restrict__ Zout, float* __restrict__ stOut,
    int N, float inv_n) {
    __shared__ unsigned short Wl[128 * 136];    // 34.8 KB
    __shared__ unsigned short Al[64 * 136];     // 17.4 KB (reused for C out)
    __shared__ float sTab[128], hTab[128], biasTab[128];
    __shared__ float redS[128], redS2[128];

    const int tid  = threadIdx.x;
    const int wv   = tid >> 6;
    const int ln   = tid & 63;
    const int half = ln >> 4;
    const int l16  = ln & 15;

    if (tid < 128) {
        biasTab[tid] = bias[tid];
        if (BN) {
            float m = stIn[tid] * inv_n;
            float v = fmaxf(stIn[128 + tid] * inv_n - m * m, 0.f);
            float s = gIn[tid] * rsqrtf(v + BN_EPS);
            sTab[tid] = s;
            hTab[tid] = tIn[tid] - m * s;
        }
        redS[tid] = 0.f; redS2[tid] = 0.f;
    }
    for (int c = tid; c < 2048; c += 256) {
        int n = c >> 4, k8 = c & 15;
        uint4 v = *(const uint4*)(Wt + n * 128 + k8 * 8);
        *(uint4*)(&Wl[n * 136 + k8 * 8]) = v;
    }
    __syncthreads();

    float cs[8], cs2[8];
#pragma unroll
    for (int i = 0; i < 8; ++i) { cs[i] = 0.f; cs2[i] = 0.f; }

    const int ntiles = (N + 63) >> 6;
    for (int tile = blockIdx.x; tile < ntiles; tile += gridDim.x) {
        const int r0 = tile * 64;
        for (int c = tid; c < 1024; c += 256) {
            int r = c >> 4, k8 = c & 15;
            int gr = r0 + r; if (gr >= N) gr = N - 1;
            uint4 v = *(const uint4*)(Zin + gr * 128 + k8 * 8);
            if (BN) {
                unsigned short* us = (unsigned short*)&v;
                int kb = k8 * 8;
#pragma unroll
                for (int j = 0; j < 8; ++j) {
                    float f = fmaxf(fmaf(bf2f(us[j]), sTab[kb + j], hTab[kb + j]), 0.f);
                    us[j] = f2bf(f);
                }
            }
            *(uint4*)(&Al[r * 136 + k8 * 8]) = v;
        }
        __syncthreads();

        short8 afrag[4];
        const int arow = wv * 16 + l16;
#pragma unroll
        for (int s = 0; s < 4; ++s)
            afrag[s] = *(const short8*)(&Al[arow * 136 + s * 32 + half * 8]);
        __syncthreads();

#pragma unroll
        for (int ct = 0; ct < 8; ++ct) {
            floatx4 acc = {0.f, 0.f, 0.f, 0.f};
            const int bn_ = ct * 16 + l16;
#pragma unroll
            for (int s = 0; s < 4; ++s) {
                short8 bfrag = *(const short8*)(&Wl[bn_ * 136 + s * 32 + half * 8]);
                acc = __builtin_amdgcn_mfma_f32_16x16x32_bf16(afrag[s], bfrag, acc, 0, 0, 0);
            }
            float bcol = biasTab[bn_];
#pragma unroll
            for (int r = 0; r < 4; ++r) {
                int lrow = wv * 16 + half * 4 + r;
                float val = acc[r] + bcol;
                if (r0 + lrow < N) { cs[ct] += val; cs2[ct] += val * val; }
                Al[lrow * 136 + bn_] = f2bf(val);
            }
        }
        __syncthreads();

        for (int c = tid; c < 1024; c += 256) {
            int r = c >> 4, k8 = c & 15;
            int gr = r0 + r;
            if (gr < N)
                *(uint4*)(Zout + gr * 128 + k8 * 8) = *(const uint4*)(&Al[r * 136 + k8 * 8]);
        }
        __syncthreads();
    }

#pragma unroll
    for (int ct = 0; ct < 8; ++ct) {
        float a = cs[ct], b = cs2[ct];
        a += __shfl_xor(a, 16); a += __shfl_xor(a, 32);
        b += __shfl_xor(b, 16); b += __shfl_xor(b, 32);
        if (half == 0) {
            atomicAdd(&redS[ct * 16 + l16], a);
            atomicAdd(&redS2[ct * 16 + l16], b);
        }
    }
    __syncthreads();
    if (tid < 128) {
        atomicAdd(stOut + tid, redS[tid]);
        atomicAdd(stOut + 128 + tid, redS2[tid]);
    }
}

// ==== final: BN+ReLU -> @wf + bf -> log_softmax, MFMA (wf padded 10->16) ====
__global__ __launch_bounds__(256) void final_mfma_k(
    const unsigned short* __restrict__ Z, const float* __restrict__ st,
    const float* __restrict__ g, const float* __restrict__ b,
    const float* __restrict__ wf, const float* __restrict__ bfc,
    float* __restrict__ out, int N, float inv_n) {
    __shared__ unsigned short Al[64 * 136];     // 17.4 KB
    __shared__ unsigned short Bl[16 * 136];     // 4.4 KB
    __shared__ float sTab[128], hTab[128], biasTab[16];

    const int tid  = threadIdx.x;
    const int wv   = tid >> 6;
    const int ln   = tid & 63;
    const int half = ln >> 4;
    const int l16  = ln & 15;

    if (tid < 128) {
        float m = st[tid] * inv_n;
        float v = fmaxf(st[128 + tid] * inv_n - m * m, 0.f);
        float s = g[tid] * rsqrtf(v + BN_EPS);
        sTab[tid] = s;
        hTab[tid] = b[tid] - m * s;
    }
    if (tid < 16) biasTab[tid] = (tid < N_CLASS) ? bfc[tid] : -3.0e38f;
    {   // Bl[n][k] = f2bf(wf[k][n]) for n<10, else 0;  16 rows x 128 k
        int n = tid >> 4, k8 = (tid & 15) * 8;
        uint4 v;
        unsigned short* us = (unsigned short*)&v;
#pragma unroll
        for (int j = 0; j < 8; ++j)
            us[j] = (n < N_CLASS) ? f2bf(wf[(k8 + j) * N_CLASS + n]) : (unsigned short)0;
        *(uint4*)(&Bl[n * 136 + k8]) = v;
    }
    __syncthreads();

    short8 bfrag[4];
#pragma unroll
    for (int s = 0; s < 4; ++s)
        bfrag[s] = *(const short8*)(&Bl[l16 * 136 + s * 32 + half * 8]);

    const int ntiles = (N + 63) >> 6;
    for (int tile = blockIdx.x; tile < ntiles; tile += gridDim.x) {
        const int r0 = tile * 64;
        for (int c = tid; c < 1024; c += 256) {
            int r = c >> 4, k8 = c & 15;
            int gr = r0 + r; if (gr >= N) gr = N - 1;
            uint4 v = *(const uint4*)(Z + gr * 128 + k8 * 8);
            unsigned short* us = (unsigned short*)&v;
            int kb = k8 * 8;
#pragma unroll
            for (int j = 0; j < 8; ++j) {
                float f = fmaxf(fmaf(bf2f(us[j]), sTab[kb + j], hTab[kb + j]), 0.f);
                us[j] = f2bf(f);
            }
            *(uint4*)(&Al[r * 136 + k8 * 8]) = v;
        }
        __syncthreads();

        short8 afrag[4];
        const int arow = wv * 16 + l16;
#pragma unroll
        for (int s = 0; s < 4; ++s)
            afrag[s] = *(const short8*)(&Al[arow * 136 + s * 32 + half * 8]);
        __syncthreads();    // Al free for next tile's staging

        floatx4 acc = {0.f, 0.f, 0.f, 0.f};
#pragma unroll
        for (int s = 0; s < 4; ++s)
            acc = __builtin_amdgcn_mfma_f32_16x16x32_bf16(afrag[s], bfrag[s], acc, 0, 0, 0);

        float bcol = biasTab[l16];
#pragma unroll
        for (int r = 0; r < 4; ++r) {
            float lg = acc[r] + bcol;                 // -3e38 for pad cols
            float mx = lg;
            mx = fmaxf(mx, __shfl_xor(mx, 1));
            mx = fmaxf(mx, __shfl_xor(mx, 2));
            mx = fmaxf(mx, __shfl_xor(mx, 4));
            mx = fmaxf(mx, __shfl_xor(mx, 8));
            float p = __expf(lg - mx);                // pad cols -> 0
            float se = p;
            se += __shfl_xor(se, 1);
            se += __shfl_xor(se, 2);
            se += __shfl_xor(se, 4);
            se += __shfl_xor(se, 8);
            float ls = __logf(se);
            int grow = r0 + wv * 16 + half * 4 + r;
            if (l16 < N_CLASS && grow < N)
                out[grow * N_CLASS + l16] = lg - mx - ls;
        }
    }
}

// ===========================================================================

extern "C" void kernel_launch(void* const* d_in, const int* in_sizes, int n_in,
                              void* d_out, int out_size, void* d_ws, size_t ws_size,
                              hipStream_t stream) {
    const float* x   = (const float*)d_in[0];
    const float* w11 = (const float*)d_in[2];
    const float* b11 = (const float*)d_in[3];
    const float* g11 = (const float*)d_in[4];
    const float* t11 = (const float*)d_in[5];
    const float* w12 = (const float*)d_in[6];
    const float* b12 = (const float*)d_in[7];
    const float* g12 = (const float*)d_in[8];
    const float* t12 = (const float*)d_in[9];
    const float* w21 = (const float*)d_in[10];
    const float* b21 = (const float*)d_in[11];
    const float* g21 = (const float*)d_in[12];
    const float* t21 = (const float*)d_in[13];
    const float* w22 = (const float*)d_in[14];
    const float* b22 = (const float*)d_in[15];
    const float* g22 = (const float*)d_in[16];
    const float* t22 = (const float*)d_in[17];
    const float* wf  = (const float*)d_in[18];
    const float* bf  = (const float*)d_in[19];
    const int*   ei  = (const int*)d_in[20];

    const int N = in_sizes[0] / N_CLASS;      // 100000
    const int E = in_sizes[1];                // 1600000
    const float inv_n = 1.0f / (float)N;

    // ---- workspace layout (16B-aligned sections) ----
    char* base = (char*)d_ws;
    size_t off = 0;
    auto take = [&](size_t bytes) { void* p = base + off; off += (bytes + 15) & ~(size_t)15; return p; };
    float*          stats   = (float*)take(1024 * 4);
    float*          xp      = (float*)take((size_t)N * 16 * 4);
    float*          h0      = (float*)take((size_t)N * 16 * 4);
    int*            cnt     = (int*)take((size_t)N * 4);
    int*            row_ptr = (int*)take((size_t)N * 4);
    int*            rank    = (int*)take((size_t)E * 4);
    int*            bsum    = (int*)take(512 * 4);
    int*            col     = (int*)take((size_t)E * 4);
    unsigned short* bufA    = (unsigned short*)take((size_t)N * HIDDEN * 2);
    unsigned short* bufB    = (unsigned short*)take((size_t)N * HIDDEN * 2);
    unsigned short* bufC    = (unsigned short*)take((size_t)N * HIDDEN * 2);
    unsigned short* Wt1     = (unsigned short*)take(128 * 128 * 2);
    unsigned short* Wt2     = (unsigned short*)take(128 * 128 * 2);
    unsigned short* Wt3     = (unsigned short*)take(128 * 128 * 2);

    const int nB = (N + 255) / 256;
    const int gE = (E + 255) / 256;

    // ---- weight prep (bf16, transposed) + zero stats/cnt, one dispatch ----
    prep_k<<<dim3(64, 3), 256, 0, stream>>>(w12, w21, w22, Wt1, Wt2, Wt3,
                                            stats, cnt, N);
    padx_k<<<(N * 16 + 255) / 256, 256, 0, stream>>>(x, xp, N);

    // ---- CSR build (by dst), atomic-free locality-passed fill ----
    hist_k<<<gE, 256, 0, stream>>>(ei, cnt, rank, E);
    scanA_k<<<nB, 256, 0, stream>>>(cnt, bsum, N);
    scanB_k<<<1, 512, 0, stream>>>(bsum, nB);
    scanC_k<<<nB, 256, 0, stream>>>(cnt, bsum, row_ptr, N);
    fill_k<<<gE, 256, 0, stream>>>(ei, rank, row_ptr, col, E, N);

    // ---- layer 1 ----
    gather10_k<<<(N * 16 + 255) / 256, 256, 0, stream>>>(xp, col, row_ptr, cnt, h0, N);
    gemm10_k<<<512, 128, 0, stream>>>(h0, w11, b11, bufA, stats, N);            // Z1 + stats0
    gemm_mfma_k<true><<<512, 256, 0, stream>>>(bufA, Wt1, b12, stats, g11, t11,
                                               bufB, stats + 256, N, inv_n);    // Z2 + stats1

    // ---- layer 2 aggregation: activate once per node, then pure-sum gather --
    act2_k<<<3125, 256, 0, stream>>>(bufB, bufC, stats + 256, g12, t12, N, inv_n);
    gather_sum_k<<<(N * 64 + 255) / 256, 256, 0, stream>>>(bufC, col, row_ptr, cnt,
                                                           bufA, N);

    // ---- layer 2 MLP ----
    gemm_mfma_k<false><<<512, 256, 0, stream>>>(bufA, Wt2, b21, nullptr, nullptr, nullptr,
                                                bufB, stats + 512, N, inv_n);   // Z3 + stats2
    gemm_mfma_k<true><<<512, 256, 0, stream>>>(bufB, Wt3, b22, stats + 512, g21, t21,
                                               bufA, stats + 768, N, inv_n);    // Z4 + stats3

    // ---- final linear + log_softmax (BN4+ReLU fused, MFMA) ----
    final_mfma_k<<<782, 256, 0, stream>>>(bufA, stats + 768, g22, t22,
                                          wf, bf, (float*)d_out, N, inv_n);
}

// Round 9
// 404.280 us; speedup vs baseline: 4.6094x; 1.0758x over previous
//
#include <hip/hip_runtime.h>

#define N_CLASS 10
#define HIDDEN 128
#define BN_EPS 1e-5f

typedef short short8 __attribute__((ext_vector_type(8)));   // 8 bf16 in 4 VGPRs
typedef float floatx4 __attribute__((ext_vector_type(4)));

__device__ __forceinline__ float bf2f(unsigned short u) {
    unsigned int x = ((unsigned int)u) << 16;
    float f; __builtin_memcpy(&f, &x, 4); return f;
}
__device__ __forceinline__ unsigned short f2bf(float f) {
    unsigned int x; __builtin_memcpy(&x, &f, 4);
    x += 0x7FFFu + ((x >> 16) & 1u);          // round-to-nearest-even
    return (unsigned short)(x >> 16);
}
// exact bf16 unpack of a packed uint, 1 VALU op each
__device__ __forceinline__ float lo_f(unsigned int u) {
    unsigned int x = u << 16; float f; __builtin_memcpy(&f, &x, 4); return f;
}
__device__ __forceinline__ float hi_f(unsigned int u) {
    unsigned int x = u & 0xffff0000u; float f; __builtin_memcpy(&f, &x, 4); return f;
}

// ================= bucketed CSR build (no per-edge global atomics) ==========
// bucket = dst >> 8  (256 dsts per bucket; NBK = ceil(N/256) = 391 <= 512)

// Phase A: global bucket histogram via per-block LDS privatization
__global__ __launch_bounds__(512) void bhist_k(const int* __restrict__ ei,
                                               int* __restrict__ bhist, int E) {
    __shared__ int h[512];
    int tid = threadIdx.x;
    h[tid] = 0;
    __syncthreads();
    for (int e = blockIdx.x * 512 + tid; e < E; e += gridDim.x * 512)
        atomicAdd(&h[((unsigned)ei[E + e]) >> 8], 1);
    __syncthreads();
    if (h[tid]) atomicAdd(&bhist[tid], h[tid]);
}

// Phase A2: exclusive scan of bucket sizes -> bstart[0..NBK], init bcur
__global__ __launch_bounds__(512) void bscan_k(const int* __restrict__ bhist,
                                               int* __restrict__ bstart,
                                               int* __restrict__ bcur, int NBK) {
    __shared__ int sm[512];
    int t = threadIdx.x;
    sm[t] = (t < NBK) ? bhist[t] : 0;
    __syncthreads();
    for (int off = 1; off < 512; off <<= 1) {
        int u = (t >= off) ? sm[t - off] : 0;
        __syncthreads();
        sm[t] += u;
        __syncthreads();
    }
    int excl = (t == 0) ? 0 : sm[t - 1];
    if (t <= NBK) bstart[t] = excl;
    if (t < NBK)  bcur[t]   = excl;
}

// Phase B: scatter (src,dst) pairs into bucket-grouped order.
// Each block claims per-bucket ranges with ONE returning atomic per bucket.
__global__ __launch_bounds__(512) void bscatter_k(const int* __restrict__ ei,
                                                  int* __restrict__ bcur,
                                                  int2* __restrict__ pairs, int E) {
    __shared__ int h[512], base[512], cur[512];
    int tid = threadIdx.x;
    h[tid] = 0; cur[tid] = 0;
    __syncthreads();
    int chunk = (E + gridDim.x - 1) / gridDim.x;
    int e0 = blockIdx.x * chunk;
    int e1 = min(e0 + chunk, E);
    for (int e = e0 + tid; e < e1; e += 512)
        atomicAdd(&h[((unsigned)ei[E + e]) >> 8], 1);
    __syncthreads();
    base[tid] = h[tid] ? atomicAdd(&bcur[tid], h[tid]) : 0;
    __syncthreads();
    for (int e = e0 + tid; e < e1; e += 512) {
        int s = ei[e], d = ei[E + e];
        int bk = ((unsigned)d) >> 8;
        int r = atomicAdd(&cur[bk], 1);      // LDS
        pairs[base[bk] + r] = make_int2(s, d);
    }
}

// Phase C: one block per bucket -> cnt, row_ptr, col. No global atomics;
// col writes confined to the bucket's ~16KB window.
__global__ __launch_bounds__(512) void bcsr_k(const int2* __restrict__ pairs,
                                              const int* __restrict__ bstart,
                                              int* __restrict__ row_ptr,
                                              int* __restrict__ cnt,
                                              int* __restrict__ col, int N) {
    __shared__ int h[256], sc[256], cur[256];
    int tid = threadIdx.x;
    if (tid < 256) { h[tid] = 0; cur[tid] = 0; }
    __syncthreads();
    int b = blockIdx.x, lo = b << 8;
    int s = bstart[b], e = bstart[b + 1];
    for (int i = s + tid; i < e; i += 512)
        atomicAdd(&h[pairs[i].y - lo], 1);   // LDS
    __syncthreads();
    if (tid < 256) sc[tid] = h[tid];
    __syncthreads();
    for (int off = 1; off < 256; off <<= 1) {
        int u = (tid < 256 && tid >= off) ? sc[tid - off] : 0;
        __syncthreads();
        if (tid < 256) sc[tid] += u;
        __syncthreads();
    }
    if (tid < 256) {
        int d = lo + tid;
        if (d < N) { cnt[d] = h[tid]; row_ptr[d] = s + sc[tid] - h[tid]; }
        sc[tid] -= h[tid];                   // exclusive, for the fill below
    }
    __syncthreads();
    for (int i = s + tid; i < e; i += 512) {
        int2 p = pairs[i];
        int d = p.y - lo;
        int r = atomicAdd(&cur[d], 1);       // LDS
        col[s + sc[d] + r] = p.x;
    }
}

// === prep: W[k][n] fp32 -> Wt[n][k] bf16 (x3) + zero stats/bhist ============
__global__ void prep_k(const float* __restrict__ W0, const float* __restrict__ W1,
                       const float* __restrict__ W2,
                       unsigned short* __restrict__ T0, unsigned short* __restrict__ T1,
                       unsigned short* __restrict__ T2,
                       float* __restrict__ stats, int* __restrict__ bhist) {
    const float* W = (blockIdx.y == 0) ? W0 : (blockIdx.y == 1) ? W1 : W2;
    unsigned short* T = (blockIdx.y == 0) ? T0 : (blockIdx.y == 1) ? T1 : T2;
    int i = blockIdx.x * 256 + threadIdx.x;
    if (i < 128 * 128) {
        int k = i >> 7, n = i & 127;
        T[n * 128 + k] = f2bf(W[k * 128 + n]);
    }
    if (blockIdx.y == 0) {
        if (i < 1024) stats[i] = 0.f;
        if (i < 512)  bhist[i] = 0;
    }
}

// ============ pad x [N,10] fp32 -> xp [N,16] fp32 (64B line rows) ===========
__global__ void padx_k(const float* __restrict__ X, float* __restrict__ XP, int N) {
    int i = blockIdx.x * 256 + threadIdx.x;
    if (i >= N * 16) return;
    int node = i >> 4, f = i & 15;
    XP[i] = (f < N_CLASS) ? X[node * N_CLASS + f] : 0.f;
}

// ========= layer-1 gather on padded rows: 16 lanes/node, 1 line/row =========
__global__ void gather10_k(const float* __restrict__ XP, const int* __restrict__ col,
                           const int* __restrict__ rp, const int* __restrict__ cnt,
                           float* __restrict__ out, int N) {
    int t = blockIdx.x * 256 + threadIdx.x;
    int node = t >> 4, f = t & 15;
    if (node >= N) return;
    int start = rp[node], deg = cnt[node];
    float acc = XP[node * 16 + f];
    int j = 0;
    for (; j + 8 <= deg; j += 8) {
        int s0 = col[start + j],     s1 = col[start + j + 1];
        int s2 = col[start + j + 2], s3 = col[start + j + 3];
        int s4 = col[start + j + 4], s5 = col[start + j + 5];
        int s6 = col[start + j + 6], s7 = col[start + j + 7];
        float v0 = XP[s0 * 16 + f];
        float v1 = XP[s1 * 16 + f];
        float v2 = XP[s2 * 16 + f];
        float v3 = XP[s3 * 16 + f];
        float v4 = XP[s4 * 16 + f];
        float v5 = XP[s5 * 16 + f];
        float v6 = XP[s6 * 16 + f];
        float v7 = XP[s7 * 16 + f];
        acc += v0; acc += v1; acc += v2; acc += v3;
        acc += v4; acc += v5; acc += v6; acc += v7;
    }
    for (; j < deg; ++j)
        acc += XP[col[start + j] * 16 + f];
    out[node * 16 + f] = acc;
}

// ======= pre-activation: R = bnrelu(Z), once per node (N x 128 bf16) ========
__global__ __launch_bounds__(256) void act2_k(
    const unsigned short* __restrict__ Z, unsigned short* __restrict__ R,
    const float* __restrict__ st, const float* __restrict__ g,
    const float* __restrict__ b, int N, float inv_n) {
    __shared__ float sTab[128], hTab[128];
    int tid = threadIdx.x;
    if (tid < 128) {
        float m = st[tid] * inv_n;
        float v = fmaxf(st[128 + tid] * inv_n - m * m, 0.f);
        float s = g[tid] * rsqrtf(v + BN_EPS);
        sTab[tid] = s;
        hTab[tid] = b[tid] - m * s;
    }
    __syncthreads();
    int total = N * 16;                       // uint4 count
    for (int i = blockIdx.x * 256 + tid; i < total; i += gridDim.x * 256) {
        int k8 = (i & 15) * 8;
        uint4 v = ((const uint4*)Z)[i];
        unsigned short* us = (unsigned short*)&v;
#pragma unroll
        for (int j = 0; j < 8; ++j) {
            float f = fmaxf(fmaf(bf2f(us[j]), sTab[k8 + j], hTab[k8 + j]), 0.f);
            us[j] = f2bf(f);
        }
        ((uint4*)R)[i] = v;
    }
}

// == layer-2 gather: pure bf16 sum; wave-scalarized CSR reads, 32-bit index ==
__global__ __launch_bounds__(256) void gather_sum_k(
    const unsigned short* __restrict__ R, const int* __restrict__ col,
    const int* __restrict__ rp, const int* __restrict__ cnt,
    unsigned short* __restrict__ out, int N) {
    int wave = __builtin_amdgcn_readfirstlane((blockIdx.x * 256 + threadIdx.x) >> 6);
    int lane = threadIdx.x & 63;
    if (wave >= N) return;
    int start = __builtin_amdgcn_readfirstlane(rp[wave]);
    int deg   = __builtin_amdgcn_readfirstlane(cnt[wave]);
    const unsigned int* Xv = (const unsigned int*)R;   // 2 bf16 per uint
    unsigned int self = Xv[wave * 64 + lane];
    float a0 = lo_f(self);
    float a1 = hi_f(self);
    int j = 0;
    for (; j + 8 <= deg; j += 8) {
        int n0 = col[start + j],     n1 = col[start + j + 1];
        int n2 = col[start + j + 2], n3 = col[start + j + 3];
        int n4 = col[start + j + 4], n5 = col[start + j + 5];
        int n6 = col[start + j + 6], n7 = col[start + j + 7];
        unsigned int w0 = Xv[n0 * 64 + lane];
        unsigned int w1 = Xv[n1 * 64 + lane];
        unsigned int w2 = Xv[n2 * 64 + lane];
        unsigned int w3 = Xv[n3 * 64 + lane];
        unsigned int w4 = Xv[n4 * 64 + lane];
        unsigned int w5 = Xv[n5 * 64 + lane];
        unsigned int w6 = Xv[n6 * 64 + lane];
        unsigned int w7 = Xv[n7 * 64 + lane];
        a0 += lo_f(w0); a1 += hi_f(w0);
        a0 += lo_f(w1); a1 += hi_f(w1);
        a0 += lo_f(w2); a1 += hi_f(w2);
        a0 += lo_f(w3); a1 += hi_f(w3);
        a0 += lo_f(w4); a1 += hi_f(w4);
        a0 += lo_f(w5); a1 += hi_f(w5);
        a0 += lo_f(w6); a1 += hi_f(w6);
        a0 += lo_f(w7); a1 += hi_f(w7);
    }
    for (; j < deg; ++j) {
        unsigned int v = Xv[col[start + j] * 64 + lane];
        a0 += lo_f(v); a1 += hi_f(v);
    }
    unsigned int o = (unsigned int)f2bf(a0) | ((unsigned int)f2bf(a1) << 16);
    ((unsigned int*)out)[wave * 64 + lane] = o;
}

// == K=10 GEMM (padded [N,16] input) + bias + fp32 col-stats, bf16 output ====
__global__ __launch_bounds__(128) void gemm10_k(
    const float* __restrict__ A, const float* __restrict__ W,
    const float* __restrict__ bias, unsigned short* __restrict__ C,
    float* __restrict__ stOut, int N) {
    __shared__ float rb[16 * 16];
    const int tid = threadIdx.x;
    float wreg[N_CLASS];
#pragma unroll
    for (int k = 0; k < N_CLASS; ++k) wreg[k] = W[k * HIDDEN + tid];
    float bb = bias[tid];
    float s = 0.f, s2 = 0.f;
    for (int r0 = blockIdx.x * 16; r0 < N; r0 += gridDim.x * 16) {
        int nr = min(16, N - r0);
        for (int i = tid; i < nr * 16; i += 128) rb[i] = A[r0 * 16 + i];
        __syncthreads();
        for (int r = 0; r < nr; ++r) {
            float acc = bb;
#pragma unroll
            for (int k = 0; k < N_CLASS; ++k) acc = fmaf(rb[r * 16 + k], wreg[k], acc);
            C[(r0 + r) * HIDDEN + tid] = f2bf(acc);
            s += acc; s2 += acc * acc;
        }
        __syncthreads();
    }
    atomicAdd(stOut + tid, s);
    atomicAdd(stOut + HIDDEN + tid, s2);
}

// ============ MFMA bf16 GEMM: Zout = [bnrelu](Zin) @ W + bias ===============
template<bool BN>
__global__ __launch_bounds__(256) void gemm_mfma_k(
    const unsigned short* __restrict__ Zin, const unsigned short* __restrict__ Wt,
    const float* __restrict__ bias,
    const float* __restrict__ stIn, const float* __restrict__ gIn,
    const float* __restrict__ tIn,
    unsigned short* __restrict__ Zout, float* __restrict__ stOut,
    int N, float inv_n) {
    __shared__ unsigned short Wl[128 * 136];    // 34.8 KB
    __shared__ unsigned short Al[64 * 136];     // 17.4 KB (reused for C out)
    __shared__ float sTab[128], hTab[128], biasTab[128];
    __shared__ float redS[128], redS2[128];

    const int tid  = threadIdx.x;
    const int wv   = tid >> 6;
    const int ln   = tid & 63;
    const int half = ln >> 4;
    const int l16  = ln & 15;

    if (tid < 128) {
        biasTab[tid] = bias[tid];
        if (BN) {
            float m = stIn[tid] * inv_n;
            float v = fmaxf(stIn[128 + tid] * inv_n - m * m, 0.f);
            float s = gIn[tid] * rsqrtf(v + BN_EPS);
            sTab[tid] = s;
            hTab[tid] = tIn[tid] - m * s;
        }
        redS[tid] = 0.f; redS2[tid] = 0.f;
    }
    for (int c = tid; c < 2048; c += 256) {
        int n = c >> 4, k8 = c & 15;
        uint4 v = *(const uint4*)(Wt + n * 128 + k8 * 8);
        *(uint4*)(&Wl[n * 136 + k8 * 8]) = v;
    }
    __syncthreads();

    float cs[8], cs2[8];
#pragma unroll
    for (int i = 0; i < 8; ++i) { cs[i] = 0.f; cs2[i] = 0.f; }

    const int ntiles = (N + 63) >> 6;
    for (int tile = blockIdx.x; tile < ntiles; tile += gridDim.x) {
        const int r0 = tile * 64;
        for (int c = tid; c < 1024; c += 256) {
            int r = c >> 4, k8 = c & 15;
            int gr = r0 + r; if (gr >= N) gr = N - 1;
            uint4 v = *(const uint4*)(Zin + gr * 128 + k8 * 8);
            if (BN) {
                unsigned short* us = (unsigned short*)&v;
                int kb = k8 * 8;
#pragma unroll
                for (int j = 0; j < 8; ++j) {
                    float f = fmaxf(fmaf(bf2f(us[j]), sTab[kb + j], hTab[kb + j]), 0.f);
                    us[j] = f2bf(f);
                }
            }
            *(uint4*)(&Al[r * 136 + k8 * 8]) = v;
        }
        __syncthreads();

        short8 afrag[4];
        const int arow = wv * 16 + l16;
#pragma unroll
        for (int s = 0; s < 4; ++s)
            afrag[s] = *(const short8*)(&Al[arow * 136 + s * 32 + half * 8]);
        __syncthreads();

#pragma unroll
        for (int ct = 0; ct < 8; ++ct) {
            floatx4 acc = {0.f, 0.f, 0.f, 0.f};
            const int bn_ = ct * 16 + l16;
#pragma unroll
            for (int s = 0; s < 4; ++s) {
                short8 bfrag = *(const short8*)(&Wl[bn_ * 136 + s * 32 + half * 8]);
                acc = __builtin_amdgcn_mfma_f32_16x16x32_bf16(afrag[s], bfrag, acc, 0, 0, 0);
            }
            float bcol = biasTab[bn_];
#pragma unroll
            for (int r = 0; r < 4; ++r) {
                int lrow = wv * 16 + half * 4 + r;
                float val = acc[r] + bcol;
                if (r0 + lrow < N) { cs[ct] += val; cs2[ct] += val * val; }
                Al[lrow * 136 + bn_] = f2bf(val);
            }
        }
        __syncthreads();

        for (int c = tid; c < 1024; c += 256) {
            int r = c >> 4, k8 = c & 15;
            int gr = r0 + r;
            if (gr < N)
                *(uint4*)(Zout + gr * 128 + k8 * 8) = *(const uint4*)(&Al[r * 136 + k8 * 8]);
        }
        __syncthreads();
    }

#pragma unroll
    for (int ct = 0; ct < 8; ++ct) {
        float a = cs[ct], b = cs2[ct];
        a += __shfl_xor(a, 16); a += __shfl_xor(a, 32);
        b += __shfl_xor(b, 16); b += __shfl_xor(b, 32);
        if (half == 0) {
            atomicAdd(&redS[ct * 16 + l16], a);
            atomicAdd(&redS2[ct * 16 + l16], b);
        }
    }
    __syncthreads();
    if (tid < 128) {
        atomicAdd(stOut + tid, redS[tid]);
        atomicAdd(stOut + 128 + tid, redS2[tid]);
    }
}

// ==== final: BN+ReLU -> @wf + bf -> log_softmax, MFMA (wf padded 10->16) ====
__global__ __launch_bounds__(256) void final_mfma_k(
    const unsigned short* __restrict__ Z, const float* __restrict__ st,
    const float* __restrict__ g, const float* __restrict__ b,
    const float* __restrict__ wf, const float* __restrict__ bfc,
    float* __restrict__ out, int N, float inv_n) {
    __shared__ unsigned short Al[64 * 136];     // 17.4 KB
    __shared__ unsigned short Bl[16 * 136];     // 4.4 KB
    __shared__ float sTab[128], hTab[128], biasTab[16];

    const int tid  = threadIdx.x;
    const int wv   = tid >> 6;
    const int ln   = tid & 63;
    const int half = ln >> 4;
    const int l16  = ln & 15;

    if (tid < 128) {
        float m = st[tid] * inv_n;
        float v = fmaxf(st[128 + tid] * inv_n - m * m, 0.f);
        float s = g[tid] * rsqrtf(v + BN_EPS);
        sTab[tid] = s;
        hTab[tid] = b[tid] - m * s;
    }
    if (tid < 16) biasTab[tid] = (tid < N_CLASS) ? bfc[tid] : -3.0e38f;
    {   // Bl[n][k] = f2bf(wf[k][n]) for n<10, else 0;  16 rows x 128 k
        int n = tid >> 4, k8 = (tid & 15) * 8;
        uint4 v;
        unsigned short* us = (unsigned short*)&v;
#pragma unroll
        for (int j = 0; j < 8; ++j)
            us[j] = (n < N_CLASS) ? f2bf(wf[(k8 + j) * N_CLASS + n]) : (unsigned short)0;
        *(uint4*)(&Bl[n * 136 + k8]) = v;
    }
    __syncthreads();

    short8 bfrag[4];
#pragma unroll
    for (int s = 0; s < 4; ++s)
        bfrag[s] = *(const short8*)(&Bl[l16 * 136 + s * 32 + half * 8]);

    const int ntiles = (N + 63) >> 6;
    for (int tile = blockIdx.x; tile < ntiles; tile += gridDim.x) {
        const int r0 = tile * 64;
        for (int c = tid; c < 1024; c += 256) {
            int r = c >> 4, k8 = c & 15;
            int gr = r0 + r; if (gr >= N) gr = N - 1;
            uint4 v = *(const uint4*)(Z + gr * 128 + k8 * 8);
            unsigned short* us = (unsigned short*)&v;
            int kb = k8 * 8;
#pragma unroll
            for (int j = 0; j < 8; ++j) {
                float f = fmaxf(fmaf(bf2f(us[j]), sTab[kb + j], hTab[kb + j]), 0.f);
                us[j] = f2bf(f);
            }
            *(uint4*)(&Al[r * 136 + k8 * 8]) = v;
        }
        __syncthreads();

        short8 afrag[4];
        const int arow = wv * 16 + l16;
#pragma unroll
        for (int s = 0; s < 4; ++s)
            afrag[s] = *(const short8*)(&Al[arow * 136 + s * 32 + half * 8]);
        __syncthreads();    // Al free for next tile's staging

        floatx4 acc = {0.f, 0.f, 0.f, 0.f};
#pragma unroll
        for (int s = 0; s < 4; ++s)
            acc = __builtin_amdgcn_mfma_f32_16x16x32_bf16(afrag[s], bfrag[s], acc, 0, 0, 0);

        float bcol = biasTab[l16];
#pragma unroll
        for (int r = 0; r < 4; ++r) {
            float lg = acc[r] + bcol;                 // -3e38 for pad cols
            float mx = lg;
            mx = fmaxf(mx, __shfl_xor(mx, 1));
            mx = fmaxf(mx, __shfl_xor(mx, 2));
            mx = fmaxf(mx, __shfl_xor(mx, 4));
            mx = fmaxf(mx, __shfl_xor(mx, 8));
            float p = __expf(lg - mx);                // pad cols -> 0
            float se = p;
            se += __shfl_xor(se, 1);
            se += __shfl_xor(se, 2);
            se += __shfl_xor(se, 4);
            se += __shfl_xor(se, 8);
            float ls = __logf(se);
            int grow = r0 + wv * 16 + half * 4 + r;
            if (l16 < N_CLASS && grow < N)
                out[grow * N_CLASS + l16] = lg - mx - ls;
        }
    }
}

// ===========================================================================

extern "C" void kernel_launch(void* const* d_in, const int* in_sizes, int n_in,
                              void* d_out, int out_size, void* d_ws, size_t ws_size,
                              hipStream_t stream) {
    const float* x   = (const float*)d_in[0];
    const float* w11 = (const float*)d_in[2];
    const float* b11 = (const float*)d_in[3];
    const float* g11 = (const float*)d_in[4];
    const float* t11 = (const float*)d_in[5];
    const float* w12 = (const float*)d_in[6];
    const float* b12 = (const float*)d_in[7];
    const float* g12 = (const float*)d_in[8];
    const float* t12 = (const float*)d_in[9];
    const float* w21 = (const float*)d_in[10];
    const float* b21 = (const float*)d_in[11];
    const float* g21 = (const float*)d_in[12];
    const float* t21 = (const float*)d_in[13];
    const float* w22 = (const float*)d_in[14];
    const float* b22 = (const float*)d_in[15];
    const float* g22 = (const float*)d_in[16];
    const float* t22 = (const float*)d_in[17];
    const float* wf  = (const float*)d_in[18];
    const float* bf  = (const float*)d_in[19];
    const int*   ei  = (const int*)d_in[20];

    const int N = in_sizes[0] / N_CLASS;      // 100000
    const int E = in_sizes[1];                // 1600000
    const float inv_n = 1.0f / (float)N;
    const int NBK = (N + 255) >> 8;           // 391 buckets (<= 512)

    // ---- workspace layout (16B-aligned sections) ----
    char* base = (char*)d_ws;
    size_t off = 0;
    auto take = [&](size_t bytes) { void* p = base + off; off += (bytes + 15) & ~(size_t)15; return p; };
    float*          stats   = (float*)take(1024 * 4);
    float*          xp      = (float*)take((size_t)N * 16 * 4);
    float*          h0      = (float*)take((size_t)N * 16 * 4);
    int*            cnt     = (int*)take((size_t)N * 4);
    int*            row_ptr = (int*)take((size_t)N * 4);
    int*            bhist   = (int*)take(512 * 4);
    int*            bstart  = (int*)take(520 * 4);
    int*            bcur    = (int*)take(512 * 4);
    int2*           pairs   = (int2*)take((size_t)E * 8);
    int*            col     = (int*)take((size_t)E * 4);
    unsigned short* bufA    = (unsigned short*)take((size_t)N * HIDDEN * 2);
    unsigned short* bufB    = (unsigned short*)take((size_t)N * HIDDEN * 2);
    unsigned short* bufC    = (unsigned short*)take((size_t)N * HIDDEN * 2);
    unsigned short* Wt1     = (unsigned short*)take(128 * 128 * 2);
    unsigned short* Wt2     = (unsigned short*)take(128 * 128 * 2);
    unsigned short* Wt3     = (unsigned short*)take(128 * 128 * 2);

    // ---- weight prep (bf16, transposed) + zero stats/bhist, one dispatch ----
    prep_k<<<dim3(64, 3), 256, 0, stream>>>(w12, w21, w22, Wt1, Wt2, Wt3,
                                            stats, bhist);
    padx_k<<<(N * 16 + 255) / 256, 256, 0, stream>>>(x, xp, N);

    // ---- bucketed CSR build (no per-edge global atomics) ----
    bhist_k<<<256, 512, 0, stream>>>(ei, bhist, E);
    bscan_k<<<1, 512, 0, stream>>>(bhist, bstart, bcur, NBK);
    bscatter_k<<<256, 512, 0, stream>>>(ei, bcur, pairs, E);
    bcsr_k<<<NBK, 512, 0, stream>>>(pairs, bstart, row_ptr, cnt, col, N);

    // ---- layer 1 ----
    gather10_k<<<(N * 16 + 255) / 256, 256, 0, stream>>>(xp, col, row_ptr, cnt, h0, N);
    gemm10_k<<<512, 128, 0, stream>>>(h0, w11, b11, bufA, stats, N);            // Z1 + stats0
    gemm_mfma_k<true><<<512, 256, 0, stream>>>(bufA, Wt1, b12, stats, g11, t11,
                                               bufB, stats + 256, N, inv_n);    // Z2 + stats1

    // ---- layer 2 aggregation: activate once per node, then pure-sum gather --
    act2_k<<<3125, 256, 0, stream>>>(bufB, bufC, stats + 256, g12, t12, N, inv_n);
    gather_sum_k<<<(N * 64 + 255) / 256, 256, 0, stream>>>(bufC, col, row_ptr, cnt,
                                                           bufA, N);

    // ---- layer 2 MLP ----
    gemm_mfma_k<false><<<512, 256, 0, stream>>>(bufA, Wt2, b21, nullptr, nullptr, nullptr,
                                                bufB, stats + 512, N, inv_n);   // Z3 + stats2
    gemm_mfma_k<true><<<512, 256, 0, stream>>>(bufB, Wt3, b22, stats + 512, g21, t21,
                                               bufA, stats + 768, N, inv_n);    // Z4 + stats3

    // ---- final linear + log_softmax (BN4+ReLU fused, MFMA) ----
    final_mfma_k<<<782, 256, 0, stream>>>(bufA, stats + 768, g22, t22,
                                          wf, bf, (float*)d_out, N, inv_n);
}